// Round 4
// baseline (395.933 us; speedup 1.0000x reference)
//
#include <hip/hip_runtime.h>

#define N_NODES 50000
#define N_EDGES 800000
#define DIM 128
#define NGRAPH 512
#define ODIM 64

typedef __attribute__((ext_vector_type(8))) short bf16x8;
typedef __attribute__((ext_vector_type(4))) short bf16x4;
typedef __attribute__((ext_vector_type(4))) float f32x4;

__device__ inline unsigned short f2bf(float f) {
  unsigned u = __builtin_bit_cast(unsigned, f);
  return (unsigned short)((u + 0x7fffu + ((u >> 16) & 1u)) >> 16);
}
__device__ inline float bf2f(unsigned short h) {
  unsigned u = ((unsigned)h) << 16;
  return __builtin_bit_cast(float, u);
}

// ---------------------------------------------------------------- embedding -> bf16
__global__ __launch_bounds__(256) void embed_kernel(
    const float* __restrict__ emb, const int* __restrict__ idx,
    unsigned short* __restrict__ x0) {
  int i = blockIdx.x * 256 + threadIdx.x;   // 16 threads/node, 8 elems each
  if (i >= N_NODES * 16) return;
  int n = i >> 4, c = i & 15;
  int v = idx[n];
  const f32x4* src = (const f32x4*)(emb + (size_t)v * DIM + c * 8);
  f32x4 a = src[0], b = src[1];
  bf16x8 o;
  #pragma unroll
  for (int e = 0; e < 4; ++e) {
    o[e] = (short)f2bf(a[e]);
    o[4 + e] = (short)f2bf(b[e]);
  }
  *(bf16x8*)(x0 + (size_t)n * DIM + c * 8) = o;
}

// ---------------------------------------------------------------- CSR build
__global__ __launch_bounds__(256) void hist_kernel(
    const int* __restrict__ ei, int* __restrict__ cnt) {
  int e = blockIdx.x * 256 + threadIdx.x;
  if (e >= N_EDGES) return;
  atomicAdd(&cnt[ei[N_EDGES + e]], 1);
}

#define VPT 8
__global__ __launch_bounds__(1024) void scan_kernel(
    const int* __restrict__ cnt, int* __restrict__ row) {
  __shared__ int wsum[16];
  __shared__ int scarry;
  int t = threadIdx.x;
  int lane = t & 63, wid = t >> 6;
  if (t == 0) scarry = 0;
  __syncthreads();
  for (int base = 0; base < N_NODES; base += 1024 * VPT) {
    int v[VPT];
    int idx0 = base + t * VPT;
    #pragma unroll
    for (int i = 0; i < VPT; ++i) {
      int idx = idx0 + i;
      v[i] = (idx < N_NODES) ? cnt[idx] : 0;
    }
    #pragma unroll
    for (int i = 1; i < VPT; ++i) v[i] += v[i - 1];
    int tsum = v[VPT - 1];
    int s = tsum;
    #pragma unroll
    for (int d = 1; d < 64; d <<= 1) {
      int u = __shfl_up(s, d, 64);
      if (lane >= d) s += u;
    }
    if (lane == 63) wsum[wid] = s;
    __syncthreads();
    if (wid == 0) {
      int ws = (lane < 16) ? wsum[lane] : 0;
      #pragma unroll
      for (int d = 1; d < 16; d <<= 1) {
        int u = __shfl_up(ws, d, 64);
        if (lane >= d) ws += u;
      }
      if (lane < 16) wsum[lane] = ws;
    }
    __syncthreads();
    int wave_excl = (wid == 0) ? 0 : wsum[wid - 1];
    int thread_excl = scarry + wave_excl + (s - tsum);
    if (idx0 < N_NODES) row[idx0] = thread_excl;
    #pragma unroll
    for (int i = 1; i < VPT; ++i) {
      int idx = idx0 + i;
      if (idx < N_NODES) row[idx] = thread_excl + v[i - 1];
    }
    __syncthreads();
    if (t == 0) scarry += wsum[15];
    __syncthreads();
  }
  if (t == 0) row[N_NODES] = scarry;
}

__global__ __launch_bounds__(256) void scatter_kernel(
    const int* __restrict__ ei, const int* __restrict__ row,
    int* __restrict__ fill, int* __restrict__ srt_src) {
  int e = blockIdx.x * 256 + threadIdx.x;
  if (e >= N_EDGES) return;
  int s = ei[e];
  int d = ei[N_EDGES + e];
  int pos = row[d] + atomicAdd(&fill[d], 1);
  srt_src[pos] = s;
}

// ---------------------------------------------------------------- fused conv: agg + 2-layer MFMA MLP
// xout = relu( Wb · relu(Wa · (x + Σ_in x_j)^T + ba) + bb )^T   (bf16 in/out, f32 accum)
// Block: 256 thr = 4 waves; 64 nodes. Gather: 8 groups × 32 lanes, 8 nodes each.
__global__ __launch_bounds__(256) void conv_kernel(
    const unsigned short* __restrict__ xin, const int* __restrict__ row,
    const int* __restrict__ srt,
    const float* __restrict__ wa, const float* __restrict__ ba,
    const float* __restrict__ wb, const float* __restrict__ bb,
    unsigned short* __restrict__ xout) {
  __shared__ short Xs[64 * 128];   // 16 KB, 16B-chunk XOR swizzle (chunk ^= row&7)
  __shared__ short Hs[64 * 128];   // 16 KB
  int t = threadIdx.x;
  int lane = t & 63;
  int w = t >> 6;
  int jq = w * 32;
  int l15 = lane & 15;
  int lg = lane >> 4;
  int nbase = blockIdx.x * 64;

  // A-operand fragments of Wa, Wb (lane l: W[jrow][ks*32 + lg*8 + e])
  bf16x8 waf[2][4], wbf[2][4];
  #pragma unroll
  for (int jm = 0; jm < 2; ++jm) {
    int jrow = jq + jm * 16 + l15;
    #pragma unroll
    for (int ks = 0; ks < 4; ++ks) {
      int k0 = ks * 32 + lg * 8;
      f32x4 a0 = *(const f32x4*)(wa + jrow * DIM + k0);
      f32x4 a1 = *(const f32x4*)(wa + jrow * DIM + k0 + 4);
      f32x4 c0 = *(const f32x4*)(wb + jrow * DIM + k0);
      f32x4 c1 = *(const f32x4*)(wb + jrow * DIM + k0 + 4);
      bf16x8 fa, fb;
      #pragma unroll
      for (int e = 0; e < 4; ++e) {
        fa[e] = (short)f2bf(a0[e]); fa[4 + e] = (short)f2bf(a1[e]);
        fb[e] = (short)f2bf(c0[e]); fb[4 + e] = (short)f2bf(c1[e]);
      }
      waf[jm][ks] = fa; wbf[jm][ks] = fb;
    }
  }
  f32x4 ba_r[2], bb_r[2];
  #pragma unroll
  for (int jm = 0; jm < 2; ++jm) {
    ba_r[jm] = *(const f32x4*)(ba + jq + jm * 16 + lg * 4);
    bb_r[jm] = *(const f32x4*)(bb + jq + jm * 16 + lg * 4);
  }

  // ---- gather phase: group g (32 lanes), lane c owns elements [4c,4c+4)
  {
    int g = t >> 5;
    int c = t & 31;
    for (int i = 0; i < 8; ++i) {
      int r = g * 8 + i;
      int node = nbase + r;
      float a0 = 0.f, a1 = 0.f, a2 = 0.f, a3 = 0.f;
      if (node < N_NODES) {
        bf16x4 sv = *(const bf16x4*)(xin + (size_t)node * DIM + c * 4);
        a0 = bf2f((unsigned short)sv[0]); a1 = bf2f((unsigned short)sv[1]);
        a2 = bf2f((unsigned short)sv[2]); a3 = bf2f((unsigned short)sv[3]);
        int lo = row[node], hi = row[node + 1];
        int k = lo;
        for (; k + 2 <= hi; k += 2) {
          int s0 = srt[k], s1 = srt[k + 1];
          bf16x4 va = *(const bf16x4*)(xin + (size_t)s0 * DIM + c * 4);
          bf16x4 vb = *(const bf16x4*)(xin + (size_t)s1 * DIM + c * 4);
          a0 += bf2f((unsigned short)va[0]) + bf2f((unsigned short)vb[0]);
          a1 += bf2f((unsigned short)va[1]) + bf2f((unsigned short)vb[1]);
          a2 += bf2f((unsigned short)va[2]) + bf2f((unsigned short)vb[2]);
          a3 += bf2f((unsigned short)va[3]) + bf2f((unsigned short)vb[3]);
        }
        if (k < hi) {
          bf16x4 va = *(const bf16x4*)(xin + (size_t)srt[k] * DIM + c * 4);
          a0 += bf2f((unsigned short)va[0]);
          a1 += bf2f((unsigned short)va[1]);
          a2 += bf2f((unsigned short)va[2]);
          a3 += bf2f((unsigned short)va[3]);
        }
      }
      bf16x4 o;
      o[0] = (short)f2bf(a0); o[1] = (short)f2bf(a1);
      o[2] = (short)f2bf(a2); o[3] = (short)f2bf(a3);
      int chunk = c >> 1;
      *(bf16x4*)&Xs[r * 128 + ((chunk ^ (r & 7)) << 3) + ((c & 1) << 2)] = o;
    }
  }
  __syncthreads();

  // ---- GEMM1: H^T tiles; D col = node-in-tile, row = j
  #pragma unroll
  for (int nt = 0; nt < 4; ++nt) {
    int rrow = nt * 16 + l15;
    bf16x8 xf[4];
    #pragma unroll
    for (int ks = 0; ks < 4; ++ks) {
      int chunk = ks * 4 + lg;
      xf[ks] = *(const bf16x8*)&Xs[rrow * 128 + ((chunk ^ (rrow & 7)) << 3)];
    }
    #pragma unroll
    for (int jm = 0; jm < 2; ++jm) {
      f32x4 acc = ba_r[jm];
      #pragma unroll
      for (int ks = 0; ks < 4; ++ks)
        acc = __builtin_amdgcn_mfma_f32_16x16x32_bf16(waf[jm][ks], xf[ks], acc, 0, 0, 0);
      int hnode = nt * 16 + l15;
      int cbase = jq + jm * 16 + lg * 4;
      unsigned p0 = (unsigned)f2bf(fmaxf(acc[0], 0.f)) |
                    ((unsigned)f2bf(fmaxf(acc[1], 0.f)) << 16);
      unsigned p1 = (unsigned)f2bf(fmaxf(acc[2], 0.f)) |
                    ((unsigned)f2bf(fmaxf(acc[3], 0.f)) << 16);
      unsigned idx = hnode * 128 + (((cbase >> 3) ^ (hnode & 7)) << 3) + (cbase & 7);
      *(uint2*)&Hs[idx] = make_uint2(p0, p1);
    }
  }
  __syncthreads();

  // ---- GEMM2: OUT tiles; store relu as bf16x4
  #pragma unroll
  for (int nt = 0; nt < 4; ++nt) {
    int rrow = nt * 16 + l15;
    bf16x8 hf[4];
    #pragma unroll
    for (int ks = 0; ks < 4; ++ks) {
      int chunk = ks * 4 + lg;
      hf[ks] = *(const bf16x8*)&Hs[rrow * 128 + ((chunk ^ (rrow & 7)) << 3)];
    }
    #pragma unroll
    for (int jm = 0; jm < 2; ++jm) {
      f32x4 acc = bb_r[jm];
      #pragma unroll
      for (int ks = 0; ks < 4; ++ks)
        acc = __builtin_amdgcn_mfma_f32_16x16x32_bf16(wbf[jm][ks], hf[ks], acc, 0, 0, 0);
      int node = nbase + nt * 16 + l15;
      if (node < N_NODES) {
        bf16x4 o;
        #pragma unroll
        for (int e = 0; e < 4; ++e) o[e] = (short)f2bf(fmaxf(acc[e], 0.f));
        *(bf16x4*)(xout + (size_t)node * DIM + jq + jm * 16 + lg * 4) = o;
      }
    }
  }
}

// ---------------------------------------------------------------- mean-pool (sorted batch) + FC
__global__ __launch_bounds__(128) void pool_fc_kernel(
    const unsigned short* __restrict__ x, const int* __restrict__ batch,
    const float* __restrict__ fcw, const float* __restrict__ fcb,
    float* __restrict__ out) {
  int g = blockIdx.x, t = threadIdx.x;
  __shared__ float pooled[DIM];
  __shared__ int sbound[2];
  if (t < 2) {
    int target = g + t;
    int lo = 0, hi = N_NODES;
    while (lo < hi) {
      int m = (lo + hi) >> 1;
      if (batch[m] < target) lo = m + 1; else hi = m;
    }
    sbound[t] = lo;
  }
  __syncthreads();
  int lo = sbound[0], hi = sbound[1];
  float s = 0.f;
  for (int nn = lo; nn < hi; ++nn) s += bf2f(x[(size_t)nn * DIM + t]);
  pooled[t] = s / fmaxf((float)(hi - lo), 1.0f);
  __syncthreads();
  if (t < ODIM) {
    float a = fcb[t];
    const float* wr = fcw + (size_t)t * DIM;
    #pragma unroll 8
    for (int h = 0; h < DIM; ++h) a += pooled[h] * wr[h];
    out[(size_t)g * ODIM + t] = a;
  }
}

// ---------------------------------------------------------------- launch
extern "C" void kernel_launch(void* const* d_in, const int* in_sizes, int n_in,
                              void* d_out, int out_size, void* d_ws, size_t ws_size,
                              hipStream_t stream) {
  const float* emb  = (const float*)d_in[0];
  const float* w1a  = (const float*)d_in[1];
  const float* b1a  = (const float*)d_in[2];
  const float* w1b  = (const float*)d_in[3];
  const float* b1b  = (const float*)d_in[4];
  const float* w2a  = (const float*)d_in[5];
  const float* b2a  = (const float*)d_in[6];
  const float* w2b  = (const float*)d_in[7];
  const float* b2b  = (const float*)d_in[8];
  const float* fcw  = (const float*)d_in[9];
  const float* fcb  = (const float*)d_in[10];
  const int*   xidx = (const int*)d_in[11];
  const int*   ei   = (const int*)d_in[12];
  const int*   batch= (const int*)d_in[13];
  float* out = (float*)d_out;

  size_t featb = (size_t)N_NODES * DIM * sizeof(unsigned short);  // 12.8 MB
  char* ws = (char*)d_ws;
  unsigned short* A = (unsigned short*)ws;              // x0 / x2
  unsigned short* C = (unsigned short*)(ws + featb);    // x1
  char* p = ws + 2 * featb;
  int* row = (int*)p;   p += ((N_NODES + 1) * 4 + 15) / 16 * 16;
  int* cnt = (int*)p;   p += (N_NODES * 4 + 15) / 16 * 16;   // also 'fill'
  int* srt = (int*)p;   // N_EDGES ints

  embed_kernel<<<(N_NODES * 16 + 255) / 256, 256, 0, stream>>>(emb, xidx, A);

  hipMemsetAsync(cnt, 0, N_NODES * sizeof(int), stream);
  hist_kernel<<<N_EDGES / 256, 256, 0, stream>>>(ei, cnt);
  scan_kernel<<<1, 1024, 0, stream>>>(cnt, row);
  hipMemsetAsync(cnt, 0, N_NODES * sizeof(int), stream);
  scatter_kernel<<<N_EDGES / 256, 256, 0, stream>>>(ei, row, cnt, srt);

  conv_kernel<<<(N_NODES + 63) / 64, 256, 0, stream>>>(A, row, srt, w1a, b1a, w1b, b1b, C);
  conv_kernel<<<(N_NODES + 63) / 64, 256, 0, stream>>>(C, row, srt, w2a, b2a, w2b, b2b, A);

  pool_fc_kernel<<<NGRAPH, 128, 0, stream>>>(A, batch, fcw, fcb, out);
}

// Round 5
// 256.627 us; speedup vs baseline: 1.5428x; 1.5428x over previous
//
#include <hip/hip_runtime.h>

#define N_NODES 50000
#define N_EDGES 800000
#define DIM 128
#define NGRAPH 512
#define ODIM 64
#define VOCAB 500
#define SCAN_NBLK ((N_NODES + 1023) / 1024)   // 49

typedef __attribute__((ext_vector_type(8))) short bf16x8;
typedef __attribute__((ext_vector_type(4))) short bf16x4;
typedef __attribute__((ext_vector_type(4))) float f32x4;

__device__ inline unsigned short f2bf(float f) {
  unsigned u = __builtin_bit_cast(unsigned, f);
  return (unsigned short)((u + 0x7fffu + ((u >> 16) & 1u)) >> 16);
}
__device__ inline float bf2f(unsigned short h) {
  unsigned u = ((unsigned)h) << 16;
  return __builtin_bit_cast(float, u);
}

// ---------------------------------------------------------------- emb f32 -> bf16 (128 KB)
__global__ __launch_bounds__(256) void emb2bf_kernel(
    const float* __restrict__ emb, unsigned short* __restrict__ embb) {
  int i = blockIdx.x * 256 + threadIdx.x;   // one bf16x8 per thread
  if (i >= VOCAB * 16) return;
  const f32x4* src = (const f32x4*)(emb + (size_t)i * 8);
  f32x4 a = src[0], b = src[1];
  bf16x8 o;
  #pragma unroll
  for (int e = 0; e < 4; ++e) {
    o[e] = (short)f2bf(a[e]);
    o[4 + e] = (short)f2bf(b[e]);
  }
  *(bf16x8*)(embb + (size_t)i * 8) = o;
}

// ---------------------------------------------------------------- CSR build
__global__ __launch_bounds__(256) void hist_kernel(
    const int* __restrict__ ei, int* __restrict__ cnt) {
  int e = blockIdx.x * 256 + threadIdx.x;
  if (e >= N_EDGES) return;
  atomicAdd(&cnt[ei[N_EDGES + e]], 1);
}

__global__ __launch_bounds__(1024) void scan_local_kernel(
    const int* __restrict__ cnt, int* __restrict__ row, int* __restrict__ bsum) {
  __shared__ int wsum[16];
  int t = threadIdx.x;
  int i = blockIdx.x * 1024 + t;
  int lane = t & 63, wid = t >> 6;
  int v = (i < N_NODES) ? cnt[i] : 0;
  int s = v;
  #pragma unroll
  for (int d = 1; d < 64; d <<= 1) {
    int u = __shfl_up(s, d, 64);
    if (lane >= d) s += u;
  }
  if (lane == 63) wsum[wid] = s;
  __syncthreads();
  if (wid == 0) {
    int ws = (lane < 16) ? wsum[lane] : 0;
    #pragma unroll
    for (int d = 1; d < 16; d <<= 1) {
      int u = __shfl_up(ws, d, 64);
      if (lane >= d) ws += u;
    }
    if (lane < 16) wsum[lane] = ws;
  }
  __syncthreads();
  int excl = s - v + (wid ? wsum[wid - 1] : 0);
  if (i < N_NODES) row[i] = excl;
  if (t == 1023) bsum[blockIdx.x] = wsum[15];
}

__global__ __launch_bounds__(64) void scan_bsum_kernel(int* __restrict__ bsum) {
  int t = threadIdx.x;
  int v = (t < SCAN_NBLK) ? bsum[t] : 0;
  int s = v;
  #pragma unroll
  for (int d = 1; d < 64; d <<= 1) {
    int u = __shfl_up(s, d, 64);
    if (t >= d) s += u;
  }
  if (t < SCAN_NBLK) bsum[t] = s - v;   // exclusive
}

__global__ __launch_bounds__(1024) void scan_add_kernel(
    int* __restrict__ row, const int* __restrict__ bsum) {
  int i = blockIdx.x * 1024 + threadIdx.x;
  if (i < N_NODES) row[i] += bsum[blockIdx.x];
  if (i == 0) row[N_NODES] = N_EDGES;
}

__global__ __launch_bounds__(256) void scatter_kernel(
    const int* __restrict__ ei, const int* __restrict__ row,
    int* __restrict__ fill, int* __restrict__ srt_src) {
  int e = blockIdx.x * 256 + threadIdx.x;
  if (e >= N_EDGES) return;
  int s = ei[e];
  int d = ei[N_EDGES + e];
  int pos = row[d] + atomicAdd(&fill[d], 1);
  srt_src[pos] = s;
}

// ---------------------------------------------------------------- agg (conv1): from emb table
// xa[n] = bf16( emb[xidx[n]] + sum_j emb[xidx[srt_j]] ) ; gather set is L2-resident (328 KB)
__global__ __launch_bounds__(256) void agg_emb_kernel(
    const unsigned short* __restrict__ embb, const int* __restrict__ xidx,
    const int* __restrict__ row, const int* __restrict__ srt,
    unsigned short* __restrict__ xa) {
  int n = blockIdx.x * 8 + (threadIdx.x >> 5);
  int c = threadIdx.x & 31;                 // 4 bf16 (8 B) per lane
  int lo = row[n], hi = row[n + 1];
  bf16x4 sv = *(const bf16x4*)(embb + (size_t)xidx[n] * DIM + c * 4);
  float a0 = bf2f((unsigned short)sv[0]), a1 = bf2f((unsigned short)sv[1]);
  float a2 = bf2f((unsigned short)sv[2]), a3 = bf2f((unsigned short)sv[3]);
  int k = lo;
  for (; k + 4 <= hi; k += 4) {
    int v0 = xidx[srt[k]], v1 = xidx[srt[k + 1]];
    int v2 = xidx[srt[k + 2]], v3 = xidx[srt[k + 3]];
    bf16x4 w0 = *(const bf16x4*)(embb + (size_t)v0 * DIM + c * 4);
    bf16x4 w1 = *(const bf16x4*)(embb + (size_t)v1 * DIM + c * 4);
    bf16x4 w2 = *(const bf16x4*)(embb + (size_t)v2 * DIM + c * 4);
    bf16x4 w3 = *(const bf16x4*)(embb + (size_t)v3 * DIM + c * 4);
    a0 += bf2f((unsigned short)w0[0]) + bf2f((unsigned short)w1[0]) +
          bf2f((unsigned short)w2[0]) + bf2f((unsigned short)w3[0]);
    a1 += bf2f((unsigned short)w0[1]) + bf2f((unsigned short)w1[1]) +
          bf2f((unsigned short)w2[1]) + bf2f((unsigned short)w3[1]);
    a2 += bf2f((unsigned short)w0[2]) + bf2f((unsigned short)w1[2]) +
          bf2f((unsigned short)w2[2]) + bf2f((unsigned short)w3[2]);
    a3 += bf2f((unsigned short)w0[3]) + bf2f((unsigned short)w1[3]) +
          bf2f((unsigned short)w2[3]) + bf2f((unsigned short)w3[3]);
  }
  for (; k < hi; ++k) {
    int v = xidx[srt[k]];
    bf16x4 w = *(const bf16x4*)(embb + (size_t)v * DIM + c * 4);
    a0 += bf2f((unsigned short)w[0]); a1 += bf2f((unsigned short)w[1]);
    a2 += bf2f((unsigned short)w[2]); a3 += bf2f((unsigned short)w[3]);
  }
  bf16x4 o;
  o[0] = (short)f2bf(a0); o[1] = (short)f2bf(a1);
  o[2] = (short)f2bf(a2); o[3] = (short)f2bf(a3);
  *(bf16x4*)(xa + (size_t)n * DIM + c * 4) = o;
}

// ---------------------------------------------------------------- agg (conv2): from node features
__global__ __launch_bounds__(256) void agg_x_kernel(
    const unsigned short* __restrict__ x, const int* __restrict__ row,
    const int* __restrict__ srt, unsigned short* __restrict__ xa) {
  int n = blockIdx.x * 8 + (threadIdx.x >> 5);
  int c = threadIdx.x & 31;
  int lo = row[n], hi = row[n + 1];
  bf16x4 sv = *(const bf16x4*)(x + (size_t)n * DIM + c * 4);
  float a0 = bf2f((unsigned short)sv[0]), a1 = bf2f((unsigned short)sv[1]);
  float a2 = bf2f((unsigned short)sv[2]), a3 = bf2f((unsigned short)sv[3]);
  int k = lo;
  for (; k + 4 <= hi; k += 4) {
    int s0 = srt[k], s1 = srt[k + 1], s2 = srt[k + 2], s3 = srt[k + 3];
    bf16x4 w0 = *(const bf16x4*)(x + (size_t)s0 * DIM + c * 4);
    bf16x4 w1 = *(const bf16x4*)(x + (size_t)s1 * DIM + c * 4);
    bf16x4 w2 = *(const bf16x4*)(x + (size_t)s2 * DIM + c * 4);
    bf16x4 w3 = *(const bf16x4*)(x + (size_t)s3 * DIM + c * 4);
    a0 += bf2f((unsigned short)w0[0]) + bf2f((unsigned short)w1[0]) +
          bf2f((unsigned short)w2[0]) + bf2f((unsigned short)w3[0]);
    a1 += bf2f((unsigned short)w0[1]) + bf2f((unsigned short)w1[1]) +
          bf2f((unsigned short)w2[1]) + bf2f((unsigned short)w3[1]);
    a2 += bf2f((unsigned short)w0[2]) + bf2f((unsigned short)w1[2]) +
          bf2f((unsigned short)w2[2]) + bf2f((unsigned short)w3[2]);
    a3 += bf2f((unsigned short)w0[3]) + bf2f((unsigned short)w1[3]) +
          bf2f((unsigned short)w2[3]) + bf2f((unsigned short)w3[3]);
  }
  for (; k < hi; ++k) {
    int s = srt[k];
    bf16x4 w = *(const bf16x4*)(x + (size_t)s * DIM + c * 4);
    a0 += bf2f((unsigned short)w[0]); a1 += bf2f((unsigned short)w[1]);
    a2 += bf2f((unsigned short)w[2]); a3 += bf2f((unsigned short)w[3]);
  }
  bf16x4 o;
  o[0] = (short)f2bf(a0); o[1] = (short)f2bf(a1);
  o[2] = (short)f2bf(a2); o[3] = (short)f2bf(a3);
  *(bf16x4*)(xa + (size_t)n * DIM + c * 4) = o;
}

// ---------------------------------------------------------------- MFMA 2-layer MLP
// xout = relu( Wb · relu(Wa · xa^T + ba) + bb )^T ; xa already = x + Σ neighbors (bf16)
__global__ __launch_bounds__(256) void mlp_mfma_kernel(
    const unsigned short* __restrict__ xa,
    const float* __restrict__ wa, const float* __restrict__ ba,
    const float* __restrict__ wb, const float* __restrict__ bb,
    unsigned short* __restrict__ xout) {
  __shared__ short Xs[64 * 128];   // 16 KB, 16B-chunk XOR swizzle (chunk ^= row&7)
  __shared__ short Hs[64 * 128];   // 16 KB
  int t = threadIdx.x;
  int lane = t & 63;
  int w = t >> 6;
  int jq = w * 32;
  int l15 = lane & 15;
  int lg = lane >> 4;
  int nbase = blockIdx.x * 64;

  // A-operand fragments of Wa, Wb (lane l: W[jrow][ks*32 + lg*8 + e])
  bf16x8 waf[2][4], wbf[2][4];
  #pragma unroll
  for (int jm = 0; jm < 2; ++jm) {
    int jrow = jq + jm * 16 + l15;
    #pragma unroll
    for (int ks = 0; ks < 4; ++ks) {
      int k0 = ks * 32 + lg * 8;
      f32x4 a0 = *(const f32x4*)(wa + jrow * DIM + k0);
      f32x4 a1 = *(const f32x4*)(wa + jrow * DIM + k0 + 4);
      f32x4 c0 = *(const f32x4*)(wb + jrow * DIM + k0);
      f32x4 c1 = *(const f32x4*)(wb + jrow * DIM + k0 + 4);
      bf16x8 fa, fb;
      #pragma unroll
      for (int e = 0; e < 4; ++e) {
        fa[e] = (short)f2bf(a0[e]); fa[4 + e] = (short)f2bf(a1[e]);
        fb[e] = (short)f2bf(c0[e]); fb[4 + e] = (short)f2bf(c1[e]);
      }
      waf[jm][ks] = fa; wbf[jm][ks] = fb;
    }
  }
  f32x4 ba_r[2], bb_r[2];
  #pragma unroll
  for (int jm = 0; jm < 2; ++jm) {
    ba_r[jm] = *(const f32x4*)(ba + jq + jm * 16 + lg * 4);
    bb_r[jm] = *(const f32x4*)(bb + jq + jm * 16 + lg * 4);
  }

  // stage: pure bf16 copy into swizzled LDS
  {
    int r = t >> 2;
    int cb = (t & 3) * 4;
    int node = nbase + r;
    #pragma unroll
    for (int i = 0; i < 4; ++i) {
      int chunk = cb + i;
      bf16x8 v = {0, 0, 0, 0, 0, 0, 0, 0};
      if (node < N_NODES)
        v = *(const bf16x8*)(xa + (size_t)node * DIM + chunk * 8);
      *(bf16x8*)&Xs[r * 128 + ((chunk ^ (r & 7)) << 3)] = v;
    }
  }
  __syncthreads();

  // GEMM1: H^T tiles; D col = node-in-tile, row = j
  #pragma unroll
  for (int nt = 0; nt < 4; ++nt) {
    int rrow = nt * 16 + l15;
    bf16x8 xf[4];
    #pragma unroll
    for (int ks = 0; ks < 4; ++ks) {
      int chunk = ks * 4 + lg;
      xf[ks] = *(const bf16x8*)&Xs[rrow * 128 + ((chunk ^ (rrow & 7)) << 3)];
    }
    #pragma unroll
    for (int jm = 0; jm < 2; ++jm) {
      f32x4 acc = ba_r[jm];
      #pragma unroll
      for (int ks = 0; ks < 4; ++ks)
        acc = __builtin_amdgcn_mfma_f32_16x16x32_bf16(waf[jm][ks], xf[ks], acc, 0, 0, 0);
      int hnode = nt * 16 + l15;
      int cbase = jq + jm * 16 + lg * 4;
      unsigned p0 = (unsigned)f2bf(fmaxf(acc[0], 0.f)) |
                    ((unsigned)f2bf(fmaxf(acc[1], 0.f)) << 16);
      unsigned p1 = (unsigned)f2bf(fmaxf(acc[2], 0.f)) |
                    ((unsigned)f2bf(fmaxf(acc[3], 0.f)) << 16);
      unsigned idx = hnode * 128 + (((cbase >> 3) ^ (hnode & 7)) << 3) + (cbase & 7);
      *(uint2*)&Hs[idx] = make_uint2(p0, p1);
    }
  }
  __syncthreads();

  // GEMM2: OUT tiles; store relu as bf16x4
  #pragma unroll
  for (int nt = 0; nt < 4; ++nt) {
    int rrow = nt * 16 + l15;
    bf16x8 hf[4];
    #pragma unroll
    for (int ks = 0; ks < 4; ++ks) {
      int chunk = ks * 4 + lg;
      hf[ks] = *(const bf16x8*)&Hs[rrow * 128 + ((chunk ^ (rrow & 7)) << 3)];
    }
    #pragma unroll
    for (int jm = 0; jm < 2; ++jm) {
      f32x4 acc = bb_r[jm];
      #pragma unroll
      for (int ks = 0; ks < 4; ++ks)
        acc = __builtin_amdgcn_mfma_f32_16x16x32_bf16(wbf[jm][ks], hf[ks], acc, 0, 0, 0);
      int node = nbase + nt * 16 + l15;
      if (node < N_NODES) {
        bf16x4 o;
        #pragma unroll
        for (int e = 0; e < 4; ++e) o[e] = (short)f2bf(fmaxf(acc[e], 0.f));
        *(bf16x4*)(xout + (size_t)node * DIM + jq + jm * 16 + lg * 4) = o;
      }
    }
  }
}

// ---------------------------------------------------------------- mean-pool (sorted batch) + FC
__global__ __launch_bounds__(128) void pool_fc_kernel(
    const unsigned short* __restrict__ x, const int* __restrict__ batch,
    const float* __restrict__ fcw, const float* __restrict__ fcb,
    float* __restrict__ out) {
  int g = blockIdx.x, t = threadIdx.x;
  __shared__ float pooled[DIM];
  __shared__ int sbound[2];
  if (t < 2) {
    int target = g + t;
    int lo = 0, hi = N_NODES;
    while (lo < hi) {
      int m = (lo + hi) >> 1;
      if (batch[m] < target) lo = m + 1; else hi = m;
    }
    sbound[t] = lo;
  }
  __syncthreads();
  int lo = sbound[0], hi = sbound[1];
  float s = 0.f;
  for (int nn = lo; nn < hi; ++nn) s += bf2f(x[(size_t)nn * DIM + t]);
  pooled[t] = s / fmaxf((float)(hi - lo), 1.0f);
  __syncthreads();
  if (t < ODIM) {
    float a = fcb[t];
    const float* wr = fcw + (size_t)t * DIM;
    #pragma unroll 8
    for (int h = 0; h < DIM; ++h) a += pooled[h] * wr[h];
    out[(size_t)g * ODIM + t] = a;
  }
}

// ---------------------------------------------------------------- launch
extern "C" void kernel_launch(void* const* d_in, const int* in_sizes, int n_in,
                              void* d_out, int out_size, void* d_ws, size_t ws_size,
                              hipStream_t stream) {
  const float* emb  = (const float*)d_in[0];
  const float* w1a  = (const float*)d_in[1];
  const float* b1a  = (const float*)d_in[2];
  const float* w1b  = (const float*)d_in[3];
  const float* b1b  = (const float*)d_in[4];
  const float* w2a  = (const float*)d_in[5];
  const float* b2a  = (const float*)d_in[6];
  const float* w2b  = (const float*)d_in[7];
  const float* b2b  = (const float*)d_in[8];
  const float* fcw  = (const float*)d_in[9];
  const float* fcb  = (const float*)d_in[10];
  const int*   xidx = (const int*)d_in[11];
  const int*   ei   = (const int*)d_in[12];
  const int*   batch= (const int*)d_in[13];
  float* out = (float*)d_out;

  size_t featb = (size_t)N_NODES * DIM * sizeof(unsigned short);  // 12.8 MB
  char* ws = (char*)d_ws;
  unsigned short* B1 = (unsigned short*)ws;             // xa (conv in)
  unsigned short* B2 = (unsigned short*)(ws + featb);   // conv out
  char* p = ws + 2 * featb;
  unsigned short* embb = (unsigned short*)p;  p += (VOCAB * DIM * 2 + 15) / 16 * 16;
  int* row  = (int*)p;  p += ((N_NODES + 1) * 4 + 15) / 16 * 16;
  int* cnt  = (int*)p;  p += (N_NODES * 4 + 15) / 16 * 16;   // also 'fill'
  int* bsum = (int*)p;  p += (SCAN_NBLK * 4 + 15) / 16 * 16;
  int* srt  = (int*)p;  // N_EDGES ints

  emb2bf_kernel<<<(VOCAB * 16 + 255) / 256, 256, 0, stream>>>(emb, embb);

  // CSR build (by dst)
  hipMemsetAsync(cnt, 0, N_NODES * sizeof(int), stream);
  hist_kernel<<<N_EDGES / 256, 256, 0, stream>>>(ei, cnt);
  scan_local_kernel<<<SCAN_NBLK, 1024, 0, stream>>>(cnt, row, bsum);
  scan_bsum_kernel<<<1, 64, 0, stream>>>(bsum);
  scan_add_kernel<<<SCAN_NBLK, 1024, 0, stream>>>(row, bsum);
  hipMemsetAsync(cnt, 0, N_NODES * sizeof(int), stream);
  scatter_kernel<<<N_EDGES / 256, 256, 0, stream>>>(ei, row, cnt, srt);

  // conv1: gather from L2-resident emb table
  agg_emb_kernel<<<N_NODES / 8, 256, 0, stream>>>(embb, xidx, row, srt, B1);
  mlp_mfma_kernel<<<(N_NODES + 63) / 64, 256, 0, stream>>>(B1, w1a, b1a, w1b, b1b, B2);

  // conv2: gather from node features
  agg_x_kernel<<<N_NODES / 8, 256, 0, stream>>>(B2, row, srt, B1);
  mlp_mfma_kernel<<<(N_NODES + 63) / 64, 256, 0, stream>>>(B1, w2a, b2a, w2b, b2b, B2);

  pool_fc_kernel<<<NGRAPH, 128, 0, stream>>>(B2, batch, fcw, fcb, out);
}

// Round 6
// 220.406 us; speedup vs baseline: 1.7964x; 1.1643x over previous
//
#include <hip/hip_runtime.h>

#define N_NODES 50000
#define N_EDGES 800000
#define DIM 128
#define NGRAPH 512
#define ODIM 64
#define VOCAB 500
#define SCAN_NBLK ((N_NODES + 1023) / 1024)   // 49

typedef __attribute__((ext_vector_type(8))) short bf16x8;
typedef __attribute__((ext_vector_type(4))) short bf16x4;
typedef __attribute__((ext_vector_type(4))) float f32x4;

__device__ inline unsigned short f2bf(float f) {
  unsigned u = __builtin_bit_cast(unsigned, f);
  return (unsigned short)((u + 0x7fffu + ((u >> 16) & 1u)) >> 16);
}
__device__ inline float bf2f(unsigned short h) {
  unsigned u = ((unsigned)h) << 16;
  return __builtin_bit_cast(float, u);
}

// ---------------------------------------------------------------- emb f32 -> bf16 (128 KB)
__global__ __launch_bounds__(256) void emb2bf_kernel(
    const float* __restrict__ emb, unsigned short* __restrict__ embb) {
  int i = blockIdx.x * 256 + threadIdx.x;   // one bf16x8 per thread
  if (i >= VOCAB * 16) return;
  const f32x4* src = (const f32x4*)(emb + (size_t)i * 8);
  f32x4 a = src[0], b = src[1];
  bf16x8 o;
  #pragma unroll
  for (int e = 0; e < 4; ++e) {
    o[e] = (short)f2bf(a[e]);
    o[4 + e] = (short)f2bf(b[e]);
  }
  *(bf16x8*)(embb + (size_t)i * 8) = o;
}

// ---------------------------------------------------------------- CSR build
// hist + per-edge rank (stable position of edge within its dst bucket)
__global__ __launch_bounds__(256) void hist_rank_kernel(
    const int* __restrict__ ei, int* __restrict__ cnt, int* __restrict__ rank) {
  int e = blockIdx.x * 256 + threadIdx.x;
  if (e >= N_EDGES) return;
  int d = ei[N_EDGES + e];
  rank[e] = atomicAdd(&cnt[d], 1);
}

__global__ __launch_bounds__(1024) void scan_local_kernel(
    const int* __restrict__ cnt, int* __restrict__ row, int* __restrict__ bsum) {
  __shared__ int wsum[16];
  int t = threadIdx.x;
  int i = blockIdx.x * 1024 + t;
  int lane = t & 63, wid = t >> 6;
  int v = (i < N_NODES) ? cnt[i] : 0;
  int s = v;
  #pragma unroll
  for (int d = 1; d < 64; d <<= 1) {
    int u = __shfl_up(s, d, 64);
    if (lane >= d) s += u;
  }
  if (lane == 63) wsum[wid] = s;
  __syncthreads();
  if (wid == 0) {
    int ws = (lane < 16) ? wsum[lane] : 0;
    #pragma unroll
    for (int d = 1; d < 16; d <<= 1) {
      int u = __shfl_up(ws, d, 64);
      if (lane >= d) ws += u;
    }
    if (lane < 16) wsum[lane] = ws;
  }
  __syncthreads();
  int excl = s - v + (wid ? wsum[wid - 1] : 0);
  if (i < N_NODES) row[i] = excl;
  if (t == 1023) bsum[blockIdx.x] = wsum[15];
}

__global__ __launch_bounds__(64) void scan_bsum_kernel(int* __restrict__ bsum) {
  int t = threadIdx.x;
  int v = (t < SCAN_NBLK) ? bsum[t] : 0;
  int s = v;
  #pragma unroll
  for (int d = 1; d < 64; d <<= 1) {
    int u = __shfl_up(s, d, 64);
    if (t >= d) s += u;
  }
  if (t < SCAN_NBLK) bsum[t] = s - v;   // exclusive
}

__global__ __launch_bounds__(1024) void scan_add_kernel(
    int* __restrict__ row, const int* __restrict__ bsum) {
  int i = blockIdx.x * 1024 + threadIdx.x;
  if (i < N_NODES) row[i] += bsum[blockIdx.x];
  if (i == 0) row[N_NODES] = N_EDGES;
}

// scatter with NO atomic: pos = row[dst] + rank[e]
__global__ __launch_bounds__(256) void scatter_kernel(
    const int* __restrict__ ei, const int* __restrict__ row,
    const int* __restrict__ rank, int* __restrict__ srt_src) {
  int e0 = (blockIdx.x * 256 + threadIdx.x) * 4;
  if (e0 + 4 <= N_EDGES) {
    int s0 = ei[e0], s1 = ei[e0 + 1], s2 = ei[e0 + 2], s3 = ei[e0 + 3];
    int d0 = ei[N_EDGES + e0], d1 = ei[N_EDGES + e0 + 1];
    int d2 = ei[N_EDGES + e0 + 2], d3 = ei[N_EDGES + e0 + 3];
    int r0 = rank[e0], r1 = rank[e0 + 1], r2 = rank[e0 + 2], r3 = rank[e0 + 3];
    int p0 = row[d0] + r0, p1 = row[d1] + r1;
    int p2 = row[d2] + r2, p3 = row[d3] + r3;
    srt_src[p0] = s0; srt_src[p1] = s1; srt_src[p2] = s2; srt_src[p3] = s3;
  } else {
    for (int e = e0; e < N_EDGES; ++e)
      srt_src[row[ei[N_EDGES + e]] + rank[e]] = ei[e];
  }
}

// ---------------------------------------------------------------- agg (conv1): from emb table
__global__ __launch_bounds__(256) void agg_emb_kernel(
    const unsigned short* __restrict__ embb, const int* __restrict__ xidx,
    const int* __restrict__ row, const int* __restrict__ srt,
    unsigned short* __restrict__ xa) {
  int n = blockIdx.x * 8 + (threadIdx.x >> 5);
  int c = threadIdx.x & 31;                 // 4 bf16 (8 B) per lane
  int lo = row[n], hi = row[n + 1];
  bf16x4 sv = *(const bf16x4*)(embb + (size_t)xidx[n] * DIM + c * 4);
  float a0 = bf2f((unsigned short)sv[0]), a1 = bf2f((unsigned short)sv[1]);
  float a2 = bf2f((unsigned short)sv[2]), a3 = bf2f((unsigned short)sv[3]);
  int k = lo;
  for (; k + 4 <= hi; k += 4) {
    int v0 = xidx[srt[k]], v1 = xidx[srt[k + 1]];
    int v2 = xidx[srt[k + 2]], v3 = xidx[srt[k + 3]];
    bf16x4 w0 = *(const bf16x4*)(embb + (size_t)v0 * DIM + c * 4);
    bf16x4 w1 = *(const bf16x4*)(embb + (size_t)v1 * DIM + c * 4);
    bf16x4 w2 = *(const bf16x4*)(embb + (size_t)v2 * DIM + c * 4);
    bf16x4 w3 = *(const bf16x4*)(embb + (size_t)v3 * DIM + c * 4);
    a0 += bf2f((unsigned short)w0[0]) + bf2f((unsigned short)w1[0]) +
          bf2f((unsigned short)w2[0]) + bf2f((unsigned short)w3[0]);
    a1 += bf2f((unsigned short)w0[1]) + bf2f((unsigned short)w1[1]) +
          bf2f((unsigned short)w2[1]) + bf2f((unsigned short)w3[1]);
    a2 += bf2f((unsigned short)w0[2]) + bf2f((unsigned short)w1[2]) +
          bf2f((unsigned short)w2[2]) + bf2f((unsigned short)w3[2]);
    a3 += bf2f((unsigned short)w0[3]) + bf2f((unsigned short)w1[3]) +
          bf2f((unsigned short)w2[3]) + bf2f((unsigned short)w3[3]);
  }
  for (; k < hi; ++k) {
    int v = xidx[srt[k]];
    bf16x4 w = *(const bf16x4*)(embb + (size_t)v * DIM + c * 4);
    a0 += bf2f((unsigned short)w[0]); a1 += bf2f((unsigned short)w[1]);
    a2 += bf2f((unsigned short)w[2]); a3 += bf2f((unsigned short)w[3]);
  }
  bf16x4 o;
  o[0] = (short)f2bf(a0); o[1] = (short)f2bf(a1);
  o[2] = (short)f2bf(a2); o[3] = (short)f2bf(a3);
  *(bf16x4*)(xa + (size_t)n * DIM + c * 4) = o;
}

// ---------------------------------------------------------------- agg (conv2): from node features
__global__ __launch_bounds__(256) void agg_x_kernel(
    const unsigned short* __restrict__ x, const int* __restrict__ row,
    const int* __restrict__ srt, unsigned short* __restrict__ xa) {
  int n = blockIdx.x * 8 + (threadIdx.x >> 5);
  int c = threadIdx.x & 31;
  int lo = row[n], hi = row[n + 1];
  bf16x4 sv = *(const bf16x4*)(x + (size_t)n * DIM + c * 4);
  float a0 = bf2f((unsigned short)sv[0]), a1 = bf2f((unsigned short)sv[1]);
  float a2 = bf2f((unsigned short)sv[2]), a3 = bf2f((unsigned short)sv[3]);
  int k = lo;
  for (; k + 4 <= hi; k += 4) {
    int s0 = srt[k], s1 = srt[k + 1], s2 = srt[k + 2], s3 = srt[k + 3];
    bf16x4 w0 = *(const bf16x4*)(x + (size_t)s0 * DIM + c * 4);
    bf16x4 w1 = *(const bf16x4*)(x + (size_t)s1 * DIM + c * 4);
    bf16x4 w2 = *(const bf16x4*)(x + (size_t)s2 * DIM + c * 4);
    bf16x4 w3 = *(const bf16x4*)(x + (size_t)s3 * DIM + c * 4);
    a0 += bf2f((unsigned short)w0[0]) + bf2f((unsigned short)w1[0]) +
          bf2f((unsigned short)w2[0]) + bf2f((unsigned short)w3[0]);
    a1 += bf2f((unsigned short)w0[1]) + bf2f((unsigned short)w1[1]) +
          bf2f((unsigned short)w2[1]) + bf2f((unsigned short)w3[1]);
    a2 += bf2f((unsigned short)w0[2]) + bf2f((unsigned short)w1[2]) +
          bf2f((unsigned short)w2[2]) + bf2f((unsigned short)w3[2]);
    a3 += bf2f((unsigned short)w0[3]) + bf2f((unsigned short)w1[3]) +
          bf2f((unsigned short)w2[3]) + bf2f((unsigned short)w3[3]);
  }
  for (; k < hi; ++k) {
    int s = srt[k];
    bf16x4 w = *(const bf16x4*)(x + (size_t)s * DIM + c * 4);
    a0 += bf2f((unsigned short)w[0]); a1 += bf2f((unsigned short)w[1]);
    a2 += bf2f((unsigned short)w[2]); a3 += bf2f((unsigned short)w[3]);
  }
  bf16x4 o;
  o[0] = (short)f2bf(a0); o[1] = (short)f2bf(a1);
  o[2] = (short)f2bf(a2); o[3] = (short)f2bf(a3);
  *(bf16x4*)(xa + (size_t)n * DIM + c * 4) = o;
}

// ---------------------------------------------------------------- MFMA 2-layer MLP
__global__ __launch_bounds__(256) void mlp_mfma_kernel(
    const unsigned short* __restrict__ xa,
    const float* __restrict__ wa, const float* __restrict__ ba,
    const float* __restrict__ wb, const float* __restrict__ bb,
    unsigned short* __restrict__ xout) {
  __shared__ short Xs[64 * 128];   // 16 KB, 16B-chunk XOR swizzle (chunk ^= row&7)
  __shared__ short Hs[64 * 128];   // 16 KB
  int t = threadIdx.x;
  int lane = t & 63;
  int w = t >> 6;
  int jq = w * 32;
  int l15 = lane & 15;
  int lg = lane >> 4;
  int nbase = blockIdx.x * 64;

  bf16x8 waf[2][4], wbf[2][4];
  #pragma unroll
  for (int jm = 0; jm < 2; ++jm) {
    int jrow = jq + jm * 16 + l15;
    #pragma unroll
    for (int ks = 0; ks < 4; ++ks) {
      int k0 = ks * 32 + lg * 8;
      f32x4 a0 = *(const f32x4*)(wa + jrow * DIM + k0);
      f32x4 a1 = *(const f32x4*)(wa + jrow * DIM + k0 + 4);
      f32x4 c0 = *(const f32x4*)(wb + jrow * DIM + k0);
      f32x4 c1 = *(const f32x4*)(wb + jrow * DIM + k0 + 4);
      bf16x8 fa, fb;
      #pragma unroll
      for (int e = 0; e < 4; ++e) {
        fa[e] = (short)f2bf(a0[e]); fa[4 + e] = (short)f2bf(a1[e]);
        fb[e] = (short)f2bf(c0[e]); fb[4 + e] = (short)f2bf(c1[e]);
      }
      waf[jm][ks] = fa; wbf[jm][ks] = fb;
    }
  }
  f32x4 ba_r[2], bb_r[2];
  #pragma unroll
  for (int jm = 0; jm < 2; ++jm) {
    ba_r[jm] = *(const f32x4*)(ba + jq + jm * 16 + lg * 4);
    bb_r[jm] = *(const f32x4*)(bb + jq + jm * 16 + lg * 4);
  }

  {
    int r = t >> 2;
    int cb = (t & 3) * 4;
    int node = nbase + r;
    #pragma unroll
    for (int i = 0; i < 4; ++i) {
      int chunk = cb + i;
      bf16x8 v = {0, 0, 0, 0, 0, 0, 0, 0};
      if (node < N_NODES)
        v = *(const bf16x8*)(xa + (size_t)node * DIM + chunk * 8);
      *(bf16x8*)&Xs[r * 128 + ((chunk ^ (r & 7)) << 3)] = v;
    }
  }
  __syncthreads();

  #pragma unroll
  for (int nt = 0; nt < 4; ++nt) {
    int rrow = nt * 16 + l15;
    bf16x8 xf[4];
    #pragma unroll
    for (int ks = 0; ks < 4; ++ks) {
      int chunk = ks * 4 + lg;
      xf[ks] = *(const bf16x8*)&Xs[rrow * 128 + ((chunk ^ (rrow & 7)) << 3)];
    }
    #pragma unroll
    for (int jm = 0; jm < 2; ++jm) {
      f32x4 acc = ba_r[jm];
      #pragma unroll
      for (int ks = 0; ks < 4; ++ks)
        acc = __builtin_amdgcn_mfma_f32_16x16x32_bf16(waf[jm][ks], xf[ks], acc, 0, 0, 0);
      int hnode = nt * 16 + l15;
      int cbase = jq + jm * 16 + lg * 4;
      unsigned p0 = (unsigned)f2bf(fmaxf(acc[0], 0.f)) |
                    ((unsigned)f2bf(fmaxf(acc[1], 0.f)) << 16);
      unsigned p1 = (unsigned)f2bf(fmaxf(acc[2], 0.f)) |
                    ((unsigned)f2bf(fmaxf(acc[3], 0.f)) << 16);
      unsigned idx = hnode * 128 + (((cbase >> 3) ^ (hnode & 7)) << 3) + (cbase & 7);
      *(uint2*)&Hs[idx] = make_uint2(p0, p1);
    }
  }
  __syncthreads();

  #pragma unroll
  for (int nt = 0; nt < 4; ++nt) {
    int rrow = nt * 16 + l15;
    bf16x8 hf[4];
    #pragma unroll
    for (int ks = 0; ks < 4; ++ks) {
      int chunk = ks * 4 + lg;
      hf[ks] = *(const bf16x8*)&Hs[rrow * 128 + ((chunk ^ (rrow & 7)) << 3)];
    }
    #pragma unroll
    for (int jm = 0; jm < 2; ++jm) {
      f32x4 acc = bb_r[jm];
      #pragma unroll
      for (int ks = 0; ks < 4; ++ks)
        acc = __builtin_amdgcn_mfma_f32_16x16x32_bf16(wbf[jm][ks], hf[ks], acc, 0, 0, 0);
      int node = nbase + nt * 16 + l15;
      if (node < N_NODES) {
        bf16x4 o;
        #pragma unroll
        for (int e = 0; e < 4; ++e) o[e] = (short)f2bf(fmaxf(acc[e], 0.f));
        *(bf16x4*)(xout + (size_t)node * DIM + jq + jm * 16 + lg * 4) = o;
      }
    }
  }
}

// ---------------------------------------------------------------- mean-pool (sorted batch) + FC
__global__ __launch_bounds__(128) void pool_fc_kernel(
    const unsigned short* __restrict__ x, const int* __restrict__ batch,
    const float* __restrict__ fcw, const float* __restrict__ fcb,
    float* __restrict__ out) {
  int g = blockIdx.x, t = threadIdx.x;
  __shared__ float pooled[DIM];
  __shared__ int sbound[2];
  if (t < 2) {
    int target = g + t;
    int lo = 0, hi = N_NODES;
    while (lo < hi) {
      int m = (lo + hi) >> 1;
      if (batch[m] < target) lo = m + 1; else hi = m;
    }
    sbound[t] = lo;
  }
  __syncthreads();
  int lo = sbound[0], hi = sbound[1];
  float s = 0.f;
  for (int nn = lo; nn < hi; ++nn) s += bf2f(x[(size_t)nn * DIM + t]);
  pooled[t] = s / fmaxf((float)(hi - lo), 1.0f);
  __syncthreads();
  if (t < ODIM) {
    float a = fcb[t];
    const float* wr = fcw + (size_t)t * DIM;
    #pragma unroll 8
    for (int h = 0; h < DIM; ++h) a += pooled[h] * wr[h];
    out[(size_t)g * ODIM + t] = a;
  }
}

// ---------------------------------------------------------------- launch
extern "C" void kernel_launch(void* const* d_in, const int* in_sizes, int n_in,
                              void* d_out, int out_size, void* d_ws, size_t ws_size,
                              hipStream_t stream) {
  const float* emb  = (const float*)d_in[0];
  const float* w1a  = (const float*)d_in[1];
  const float* b1a  = (const float*)d_in[2];
  const float* w1b  = (const float*)d_in[3];
  const float* b1b  = (const float*)d_in[4];
  const float* w2a  = (const float*)d_in[5];
  const float* b2a  = (const float*)d_in[6];
  const float* w2b  = (const float*)d_in[7];
  const float* b2b  = (const float*)d_in[8];
  const float* fcw  = (const float*)d_in[9];
  const float* fcb  = (const float*)d_in[10];
  const int*   xidx = (const int*)d_in[11];
  const int*   ei   = (const int*)d_in[12];
  const int*   batch= (const int*)d_in[13];
  float* out = (float*)d_out;

  size_t featb = (size_t)N_NODES * DIM * sizeof(unsigned short);  // 12.8 MB
  char* ws = (char*)d_ws;
  unsigned short* B1 = (unsigned short*)ws;             // xa (conv in)
  unsigned short* B2 = (unsigned short*)(ws + featb);   // conv out
  char* p = ws + 2 * featb;
  unsigned short* embb = (unsigned short*)p;  p += (VOCAB * DIM * 2 + 15) / 16 * 16;
  int* row  = (int*)p;  p += ((N_NODES + 1) * 4 + 15) / 16 * 16;
  int* cnt  = (int*)p;  p += (N_NODES * 4 + 15) / 16 * 16;
  int* bsum = (int*)p;  p += (SCAN_NBLK * 4 + 15) / 16 * 16;
  int* rank = (int*)p;  p += (size_t)N_EDGES * 4;
  int* srt  = (int*)p;  // N_EDGES ints

  emb2bf_kernel<<<(VOCAB * 16 + 255) / 256, 256, 0, stream>>>(emb, embb);

  // CSR build (by dst): hist+rank -> scan -> rank-based scatter (no atomics)
  hipMemsetAsync(cnt, 0, N_NODES * sizeof(int), stream);
  hist_rank_kernel<<<N_EDGES / 256, 256, 0, stream>>>(ei, cnt, rank);
  scan_local_kernel<<<SCAN_NBLK, 1024, 0, stream>>>(cnt, row, bsum);
  scan_bsum_kernel<<<1, 64, 0, stream>>>(bsum);
  scan_add_kernel<<<SCAN_NBLK, 1024, 0, stream>>>(row, bsum);
  scatter_kernel<<<(N_EDGES / 4 + 255) / 256, 256, 0, stream>>>(ei, row, rank, srt);

  // conv1: gather from L2-resident emb table
  agg_emb_kernel<<<N_NODES / 8, 256, 0, stream>>>(embb, xidx, row, srt, B1);
  mlp_mfma_kernel<<<(N_NODES + 63) / 64, 256, 0, stream>>>(B1, w1a, b1a, w1b, b1b, B2);

  // conv2: gather from node features
  agg_x_kernel<<<N_NODES / 8, 256, 0, stream>>>(B2, row, srt, B1);
  mlp_mfma_kernel<<<(N_NODES + 63) / 64, 256, 0, stream>>>(B1, w2a, b2a, w2b, b2b, B2);

  pool_fc_kernel<<<NGRAPH, 128, 0, stream>>>(B2, batch, fcw, fcb, out);
}

// Round 7
// 176.140 us; speedup vs baseline: 2.2478x; 1.2513x over previous
//
#include <hip/hip_runtime.h>

#define N_NODES 50000
#define N_EDGES 800000
#define DIM 128
#define NGRAPH 512
#define ODIM 64
#define VOCAB 500
#define SCAN_NBLK ((N_NODES + 1023) / 1024)   // 49

typedef __attribute__((ext_vector_type(8))) short bf16x8;
typedef __attribute__((ext_vector_type(4))) short bf16x4;
typedef __attribute__((ext_vector_type(4))) float f32x4;

__device__ inline unsigned short f2bf(float f) {
  unsigned u = __builtin_bit_cast(unsigned, f);
  return (unsigned short)((u + 0x7fffu + ((u >> 16) & 1u)) >> 16);
}
__device__ inline float bf2f(unsigned short h) {
  unsigned u = ((unsigned)h) << 16;
  return __builtin_bit_cast(float, u);
}

// ---------------------------------------------------------------- emb f32 -> bf16 (128 KB)
__global__ __launch_bounds__(256) void emb2bf_kernel(
    const float* __restrict__ emb, unsigned short* __restrict__ embb) {
  int i = blockIdx.x * 256 + threadIdx.x;
  if (i >= VOCAB * 16) return;
  const f32x4* src = (const f32x4*)(emb + (size_t)i * 8);
  f32x4 a = src[0], b = src[1];
  bf16x8 o;
  #pragma unroll
  for (int e = 0; e < 4; ++e) {
    o[e] = (short)f2bf(a[e]);
    o[4 + e] = (short)f2bf(b[e]);
  }
  *(bf16x8*)(embb + (size_t)i * 8) = o;
}

// ---------------------------------------------------------------- CSR build
__global__ __launch_bounds__(256) void hist_rank_kernel(
    const int* __restrict__ ei, int* __restrict__ cnt, int* __restrict__ rank) {
  int e0 = (blockIdx.x * 256 + threadIdx.x) * 4;
  if (e0 + 4 <= N_EDGES) {
    int d0 = ei[N_EDGES + e0],     d1 = ei[N_EDGES + e0 + 1];
    int d2 = ei[N_EDGES + e0 + 2], d3 = ei[N_EDGES + e0 + 3];
    int r0 = atomicAdd(&cnt[d0], 1);
    int r1 = atomicAdd(&cnt[d1], 1);
    int r2 = atomicAdd(&cnt[d2], 1);
    int r3 = atomicAdd(&cnt[d3], 1);
    rank[e0] = r0; rank[e0 + 1] = r1; rank[e0 + 2] = r2; rank[e0 + 3] = r3;
  } else {
    for (int e = e0; e < N_EDGES; ++e)
      rank[e] = atomicAdd(&cnt[ei[N_EDGES + e]], 1);
  }
}

__global__ __launch_bounds__(1024) void scan_local_kernel(
    const int* __restrict__ cnt, int* __restrict__ row, int* __restrict__ bsum) {
  __shared__ int wsum[16];
  int t = threadIdx.x;
  int i = blockIdx.x * 1024 + t;
  int lane = t & 63, wid = t >> 6;
  int v = (i < N_NODES) ? cnt[i] : 0;
  int s = v;
  #pragma unroll
  for (int d = 1; d < 64; d <<= 1) {
    int u = __shfl_up(s, d, 64);
    if (lane >= d) s += u;
  }
  if (lane == 63) wsum[wid] = s;
  __syncthreads();
  if (wid == 0) {
    int ws = (lane < 16) ? wsum[lane] : 0;
    #pragma unroll
    for (int d = 1; d < 16; d <<= 1) {
      int u = __shfl_up(ws, d, 64);
      if (lane >= d) ws += u;
    }
    if (lane < 16) wsum[lane] = ws;
  }
  __syncthreads();
  int excl = s - v + (wid ? wsum[wid - 1] : 0);
  if (i < N_NODES) row[i] = excl;
  if (t == 1023) bsum[blockIdx.x] = wsum[15];
}

// adds prefix of bsum (exclusive, computed in-block) to row; also sets row[N]
__global__ __launch_bounds__(1024) void scan_add_kernel(
    int* __restrict__ row, const int* __restrict__ bsum) {
  __shared__ int soff;
  int t = threadIdx.x;
  if (t < 64) {
    int v = (t < (int)blockIdx.x && t < SCAN_NBLK) ? bsum[t] : 0;
    #pragma unroll
    for (int d = 32; d >= 1; d >>= 1) v += __shfl_down(v, d, 64);
    if (t == 0) soff = v;
  }
  __syncthreads();
  int i = blockIdx.x * 1024 + t;
  if (i < N_NODES) row[i] += soff;
  if (i == 0) row[N_NODES] = N_EDGES;
}

// scatter with NO atomic: pos = row[dst] + rank[e]
__global__ __launch_bounds__(256) void scatter_kernel(
    const int* __restrict__ ei, const int* __restrict__ row,
    const int* __restrict__ rank, int* __restrict__ srt_src) {
  int e0 = (blockIdx.x * 256 + threadIdx.x) * 4;
  if (e0 + 4 <= N_EDGES) {
    int s0 = ei[e0], s1 = ei[e0 + 1], s2 = ei[e0 + 2], s3 = ei[e0 + 3];
    int d0 = ei[N_EDGES + e0], d1 = ei[N_EDGES + e0 + 1];
    int d2 = ei[N_EDGES + e0 + 2], d3 = ei[N_EDGES + e0 + 3];
    int r0 = rank[e0], r1 = rank[e0 + 1], r2 = rank[e0 + 2], r3 = rank[e0 + 3];
    srt_src[row[d0] + r0] = s0; srt_src[row[d1] + r1] = s1;
    srt_src[row[d2] + r2] = s2; srt_src[row[d3] + r3] = s3;
  } else {
    for (int e = e0; e < N_EDGES; ++e)
      srt_src[row[ei[N_EDGES + e]] + rank[e]] = ei[e];
  }
}

// ---------------------------------------------------------------- agg (conv1): from emb table
// 16 lanes/node, bf16x8 (16 B) per lane; 16 nodes per 256-block
__global__ __launch_bounds__(256) void agg_emb_kernel(
    const unsigned short* __restrict__ embb, const int* __restrict__ xidx,
    const int* __restrict__ row, const int* __restrict__ srt,
    unsigned short* __restrict__ xa) {
  int n = blockIdx.x * 16 + (threadIdx.x >> 4);
  int c = threadIdx.x & 15;
  int lo = row[n], hi = row[n + 1];
  bf16x8 sv = *(const bf16x8*)(embb + (size_t)xidx[n] * DIM + c * 8);
  float a[8];
  #pragma unroll
  for (int e = 0; e < 8; ++e) a[e] = bf2f((unsigned short)sv[e]);
  int k = lo;
  for (; k + 4 <= hi; k += 4) {
    int v0 = xidx[srt[k]],     v1 = xidx[srt[k + 1]];
    int v2 = xidx[srt[k + 2]], v3 = xidx[srt[k + 3]];
    bf16x8 w0 = *(const bf16x8*)(embb + (size_t)v0 * DIM + c * 8);
    bf16x8 w1 = *(const bf16x8*)(embb + (size_t)v1 * DIM + c * 8);
    bf16x8 w2 = *(const bf16x8*)(embb + (size_t)v2 * DIM + c * 8);
    bf16x8 w3 = *(const bf16x8*)(embb + (size_t)v3 * DIM + c * 8);
    #pragma unroll
    for (int e = 0; e < 8; ++e)
      a[e] += bf2f((unsigned short)w0[e]) + bf2f((unsigned short)w1[e]) +
              bf2f((unsigned short)w2[e]) + bf2f((unsigned short)w3[e]);
  }
  for (; k < hi; ++k) {
    int v = xidx[srt[k]];
    bf16x8 w = *(const bf16x8*)(embb + (size_t)v * DIM + c * 8);
    #pragma unroll
    for (int e = 0; e < 8; ++e) a[e] += bf2f((unsigned short)w[e]);
  }
  bf16x8 o;
  #pragma unroll
  for (int e = 0; e < 8; ++e) o[e] = (short)f2bf(a[e]);
  *(bf16x8*)(xa + (size_t)n * DIM + c * 8) = o;
}

// ---------------------------------------------------------------- agg (conv2): from node features
__global__ __launch_bounds__(256) void agg_x_kernel(
    const unsigned short* __restrict__ x, const int* __restrict__ row,
    const int* __restrict__ srt, unsigned short* __restrict__ xa) {
  int n = blockIdx.x * 16 + (threadIdx.x >> 4);
  int c = threadIdx.x & 15;
  int lo = row[n], hi = row[n + 1];
  bf16x8 sv = *(const bf16x8*)(x + (size_t)n * DIM + c * 8);
  float a[8];
  #pragma unroll
  for (int e = 0; e < 8; ++e) a[e] = bf2f((unsigned short)sv[e]);
  int k = lo;
  for (; k + 4 <= hi; k += 4) {
    int s0 = srt[k], s1 = srt[k + 1], s2 = srt[k + 2], s3 = srt[k + 3];
    bf16x8 w0 = *(const bf16x8*)(x + (size_t)s0 * DIM + c * 8);
    bf16x8 w1 = *(const bf16x8*)(x + (size_t)s1 * DIM + c * 8);
    bf16x8 w2 = *(const bf16x8*)(x + (size_t)s2 * DIM + c * 8);
    bf16x8 w3 = *(const bf16x8*)(x + (size_t)s3 * DIM + c * 8);
    #pragma unroll
    for (int e = 0; e < 8; ++e)
      a[e] += bf2f((unsigned short)w0[e]) + bf2f((unsigned short)w1[e]) +
              bf2f((unsigned short)w2[e]) + bf2f((unsigned short)w3[e]);
  }
  for (; k < hi; ++k) {
    int s = srt[k];
    bf16x8 w = *(const bf16x8*)(x + (size_t)s * DIM + c * 8);
    #pragma unroll
    for (int e = 0; e < 8; ++e) a[e] += bf2f((unsigned short)w[e]);
  }
  bf16x8 o;
  #pragma unroll
  for (int e = 0; e < 8; ++e) o[e] = (short)f2bf(a[e]);
  *(bf16x8*)(xa + (size_t)n * DIM + c * 8) = o;
}

// ---------------------------------------------------------------- MFMA 2-layer MLP
__global__ __launch_bounds__(256) void mlp_mfma_kernel(
    const unsigned short* __restrict__ xa,
    const float* __restrict__ wa, const float* __restrict__ ba,
    const float* __restrict__ wb, const float* __restrict__ bb,
    unsigned short* __restrict__ xout) {
  __shared__ short Xs[64 * 128];   // 16 KB, 16B-chunk XOR swizzle (chunk ^= row&7)
  __shared__ short Hs[64 * 128];   // 16 KB
  int t = threadIdx.x;
  int lane = t & 63;
  int w = t >> 6;
  int jq = w * 32;
  int l15 = lane & 15;
  int lg = lane >> 4;
  int nbase = blockIdx.x * 64;

  bf16x8 waf[2][4], wbf[2][4];
  #pragma unroll
  for (int jm = 0; jm < 2; ++jm) {
    int jrow = jq + jm * 16 + l15;
    #pragma unroll
    for (int ks = 0; ks < 4; ++ks) {
      int k0 = ks * 32 + lg * 8;
      f32x4 a0 = *(const f32x4*)(wa + jrow * DIM + k0);
      f32x4 a1 = *(const f32x4*)(wa + jrow * DIM + k0 + 4);
      f32x4 c0 = *(const f32x4*)(wb + jrow * DIM + k0);
      f32x4 c1 = *(const f32x4*)(wb + jrow * DIM + k0 + 4);
      bf16x8 fa, fb;
      #pragma unroll
      for (int e = 0; e < 4; ++e) {
        fa[e] = (short)f2bf(a0[e]); fa[4 + e] = (short)f2bf(a1[e]);
        fb[e] = (short)f2bf(c0[e]); fb[4 + e] = (short)f2bf(c1[e]);
      }
      waf[jm][ks] = fa; wbf[jm][ks] = fb;
    }
  }
  f32x4 ba_r[2], bb_r[2];
  #pragma unroll
  for (int jm = 0; jm < 2; ++jm) {
    ba_r[jm] = *(const f32x4*)(ba + jq + jm * 16 + lg * 4);
    bb_r[jm] = *(const f32x4*)(bb + jq + jm * 16 + lg * 4);
  }

  {
    int r = t >> 2;
    int cb = (t & 3) * 4;
    int node = nbase + r;
    #pragma unroll
    for (int i = 0; i < 4; ++i) {
      int chunk = cb + i;
      bf16x8 v = {0, 0, 0, 0, 0, 0, 0, 0};
      if (node < N_NODES)
        v = *(const bf16x8*)(xa + (size_t)node * DIM + chunk * 8);
      *(bf16x8*)&Xs[r * 128 + ((chunk ^ (r & 7)) << 3)] = v;
    }
  }
  __syncthreads();

  #pragma unroll
  for (int nt = 0; nt < 4; ++nt) {
    int rrow = nt * 16 + l15;
    bf16x8 xf[4];
    #pragma unroll
    for (int ks = 0; ks < 4; ++ks) {
      int chunk = ks * 4 + lg;
      xf[ks] = *(const bf16x8*)&Xs[rrow * 128 + ((chunk ^ (rrow & 7)) << 3)];
    }
    #pragma unroll
    for (int jm = 0; jm < 2; ++jm) {
      f32x4 acc = ba_r[jm];
      #pragma unroll
      for (int ks = 0; ks < 4; ++ks)
        acc = __builtin_amdgcn_mfma_f32_16x16x32_bf16(waf[jm][ks], xf[ks], acc, 0, 0, 0);
      int hnode = nt * 16 + l15;
      int cbase = jq + jm * 16 + lg * 4;
      unsigned p0 = (unsigned)f2bf(fmaxf(acc[0], 0.f)) |
                    ((unsigned)f2bf(fmaxf(acc[1], 0.f)) << 16);
      unsigned p1 = (unsigned)f2bf(fmaxf(acc[2], 0.f)) |
                    ((unsigned)f2bf(fmaxf(acc[3], 0.f)) << 16);
      unsigned idx = hnode * 128 + (((cbase >> 3) ^ (hnode & 7)) << 3) + (cbase & 7);
      *(uint2*)&Hs[idx] = make_uint2(p0, p1);
    }
  }
  __syncthreads();

  #pragma unroll
  for (int nt = 0; nt < 4; ++nt) {
    int rrow = nt * 16 + l15;
    bf16x8 hf[4];
    #pragma unroll
    for (int ks = 0; ks < 4; ++ks) {
      int chunk = ks * 4 + lg;
      hf[ks] = *(const bf16x8*)&Hs[rrow * 128 + ((chunk ^ (rrow & 7)) << 3)];
    }
    #pragma unroll
    for (int jm = 0; jm < 2; ++jm) {
      f32x4 acc = bb_r[jm];
      #pragma unroll
      for (int ks = 0; ks < 4; ++ks)
        acc = __builtin_amdgcn_mfma_f32_16x16x32_bf16(wbf[jm][ks], hf[ks], acc, 0, 0, 0);
      int node = nbase + nt * 16 + l15;
      if (node < N_NODES) {
        bf16x4 o;
        #pragma unroll
        for (int e = 0; e < 4; ++e) o[e] = (short)f2bf(fmaxf(acc[e], 0.f));
        *(bf16x4*)(xout + (size_t)node * DIM + jq + jm * 16 + lg * 4) = o;
      }
    }
  }
}

// ---------------------------------------------------------------- mean-pool + FC (row-parallel)
#define PP 132   // padded pitch for partials
__global__ __launch_bounds__(256) void pool_fc_kernel(
    const unsigned short* __restrict__ x, const int* __restrict__ batch,
    const float* __restrict__ fcw, const float* __restrict__ fcb,
    float* __restrict__ out) {
  int g = blockIdx.x, t = threadIdx.x;
  __shared__ float part[16 * PP];   // 8.25 KB
  __shared__ float pooled[DIM];
  __shared__ int sbound[2];
  if (t < 2) {
    int target = g + t;
    int lo = 0, hi = N_NODES;
    while (lo < hi) {
      int m = (lo + hi) >> 1;
      if (batch[m] < target) lo = m + 1; else hi = m;
    }
    sbound[t] = lo;
  }
  __syncthreads();
  int lo = sbound[0], hi = sbound[1];
  int r = t >> 4, c = t & 15;
  float acc[8] = {0.f, 0.f, 0.f, 0.f, 0.f, 0.f, 0.f, 0.f};
  for (int nn = lo + r; nn < hi; nn += 16) {
    bf16x8 v = *(const bf16x8*)(x + (size_t)nn * DIM + c * 8);
    #pragma unroll
    for (int e = 0; e < 8; ++e) acc[e] += bf2f((unsigned short)v[e]);
  }
  #pragma unroll
  for (int e = 0; e < 8; ++e) part[r * PP + c * 8 + e] = acc[e];
  __syncthreads();
  if (t < DIM) {
    float s = 0.f;
    #pragma unroll
    for (int rr = 0; rr < 16; ++rr) s += part[rr * PP + t];
    pooled[t] = s / fmaxf((float)(hi - lo), 1.0f);
  }
  __syncthreads();
  if (t < ODIM) {
    float a = fcb[t];
    const float* wr = fcw + (size_t)t * DIM;
    #pragma unroll 8
    for (int h = 0; h < DIM; ++h) a += pooled[h] * wr[h];
    out[(size_t)g * ODIM + t] = a;
  }
}

// ---------------------------------------------------------------- launch
extern "C" void kernel_launch(void* const* d_in, const int* in_sizes, int n_in,
                              void* d_out, int out_size, void* d_ws, size_t ws_size,
                              hipStream_t stream) {
  const float* emb  = (const float*)d_in[0];
  const float* w1a  = (const float*)d_in[1];
  const float* b1a  = (const float*)d_in[2];
  const float* w1b  = (const float*)d_in[3];
  const float* b1b  = (const float*)d_in[4];
  const float* w2a  = (const float*)d_in[5];
  const float* b2a  = (const float*)d_in[6];
  const float* w2b  = (const float*)d_in[7];
  const float* b2b  = (const float*)d_in[8];
  const float* fcw  = (const float*)d_in[9];
  const float* fcb  = (const float*)d_in[10];
  const int*   xidx = (const int*)d_in[11];
  const int*   ei   = (const int*)d_in[12];
  const int*   batch= (const int*)d_in[13];
  float* out = (float*)d_out;

  size_t featb = (size_t)N_NODES * DIM * sizeof(unsigned short);  // 12.8 MB
  char* ws = (char*)d_ws;
  unsigned short* B1 = (unsigned short*)ws;             // xa (conv in)
  unsigned short* B2 = (unsigned short*)(ws + featb);   // conv out
  char* p = ws + 2 * featb;
  unsigned short* embb = (unsigned short*)p;  p += (VOCAB * DIM * 2 + 15) / 16 * 16;
  int* row  = (int*)p;  p += ((N_NODES + 1) * 4 + 15) / 16 * 16;
  int* cnt  = (int*)p;  p += (N_NODES * 4 + 15) / 16 * 16;
  int* bsum = (int*)p;  p += (SCAN_NBLK * 4 + 15) / 16 * 16;
  int* rank = (int*)p;  p += (size_t)N_EDGES * 4;
  int* srt  = (int*)p;  // N_EDGES ints

  emb2bf_kernel<<<(VOCAB * 16 + 255) / 256, 256, 0, stream>>>(emb, embb);

  // CSR build (by dst): hist+rank -> scan -> rank-based scatter (no atomics)
  hipMemsetAsync(cnt, 0, N_NODES * sizeof(int), stream);
  hist_rank_kernel<<<(N_EDGES / 4 + 255) / 256, 256, 0, stream>>>(ei, cnt, rank);
  scan_local_kernel<<<SCAN_NBLK, 1024, 0, stream>>>(cnt, row, bsum);
  scan_add_kernel<<<SCAN_NBLK, 1024, 0, stream>>>(row, bsum);
  scatter_kernel<<<(N_EDGES / 4 + 255) / 256, 256, 0, stream>>>(ei, row, rank, srt);

  // conv1: gather from L2-resident emb table
  agg_emb_kernel<<<N_NODES / 16, 256, 0, stream>>>(embb, xidx, row, srt, B1);
  mlp_mfma_kernel<<<(N_NODES + 63) / 64, 256, 0, stream>>>(B1, w1a, b1a, w1b, b1b, B2);

  // conv2: gather from node features
  agg_x_kernel<<<N_NODES / 16, 256, 0, stream>>>(B2, row, srt, B1);
  mlp_mfma_kernel<<<(N_NODES + 63) / 64, 256, 0, stream>>>(B1, w2a, b2a, w2b, b2b, B2);

  pool_fc_kernel<<<NGRAPH, 256, 0, stream>>>(B2, batch, fcw, fcb, out);
}

// Round 8
// 176.138 us; speedup vs baseline: 2.2479x; 1.0000x over previous
//
#include <hip/hip_runtime.h>

#define N_NODES 50000
#define N_EDGES 800000
#define DIM 128
#define NGRAPH 512
#define ODIM 64
#define VOCAB 500
#define SCAN_NBLK ((N_NODES + 1023) / 1024)   // 49
#define NB 64                                  // edge-partition blocks for counting sort
#define EPB (N_EDGES / NB)                     // 12500
#define NWORDS (N_NODES / 2)                   // 25000 packed u16-pair words

typedef __attribute__((ext_vector_type(8))) short bf16x8;
typedef __attribute__((ext_vector_type(4))) short bf16x4;
typedef __attribute__((ext_vector_type(4))) float f32x4;

__device__ inline unsigned short f2bf(float f) {
  unsigned u = __builtin_bit_cast(unsigned, f);
  return (unsigned short)((u + 0x7fffu + ((u >> 16) & 1u)) >> 16);
}
__device__ inline float bf2f(unsigned short h) {
  unsigned u = ((unsigned)h) << 16;
  return __builtin_bit_cast(float, u);
}

// ---------------------------------------------------------------- emb f32 -> bf16 (128 KB)
__global__ __launch_bounds__(256) void emb2bf_kernel(
    const float* __restrict__ emb, unsigned short* __restrict__ embb) {
  int i = blockIdx.x * 256 + threadIdx.x;
  if (i >= VOCAB * 16) return;
  const f32x4* src = (const f32x4*)(emb + (size_t)i * 8);
  f32x4 a = src[0], b = src[1];
  bf16x8 o;
  #pragma unroll
  for (int e = 0; e < 4; ++e) {
    o[e] = (short)f2bf(a[e]);
    o[4 + e] = (short)f2bf(b[e]);
  }
  *(bf16x8*)(embb + (size_t)i * 8) = o;
}

// ---------------------------------------------------------------- CSR build: LDS counting sort
// pass 1: per-block private histogram (u16 pairs packed in u32), no global atomics
__global__ __launch_bounds__(1024) void hist_pass_kernel(
    const int* __restrict__ ei, unsigned* __restrict__ H) {
  __shared__ unsigned cnt[NWORDS];   // 100 KB
  int t = threadIdx.x, b = blockIdx.x;
  for (int i = t; i < NWORDS; i += 1024) cnt[i] = 0;
  __syncthreads();
  int base = b * EPB;
  for (int i = t; i < EPB; i += 1024) {
    int d = ei[N_EDGES + base + i];
    atomicAdd(&cnt[d >> 1], 1u << ((d & 1) * 16));
  }
  __syncthreads();
  unsigned* Hb = H + (size_t)b * NWORDS;
  for (int i = t; i < NWORDS; i += 1024) Hb[i] = cnt[i];
}

// column-wise exclusive prefix over blocks: P[b][d] = sum_{b'<b} H[b'][d]; deg[d] = total
__global__ __launch_bounds__(256) void transpose_scan_kernel(
    const unsigned* __restrict__ H, unsigned* __restrict__ P,
    int* __restrict__ deg) {
  int w = blockIdx.x * 256 + threadIdx.x;
  if (w >= NWORDS) return;
  unsigned lo = 0, hi = 0;
  for (int b = 0; b < NB; ++b) {
    unsigned h = H[(size_t)b * NWORDS + w];
    P[(size_t)b * NWORDS + w] = lo | (hi << 16);
    lo += h & 0xFFFFu;
    hi += h >> 16;
  }
  deg[2 * w] = (int)lo;
  deg[2 * w + 1] = (int)hi;
}

__global__ __launch_bounds__(1024) void scan_local_kernel(
    const int* __restrict__ cnt, int* __restrict__ row, int* __restrict__ bsum) {
  __shared__ int wsum[16];
  int t = threadIdx.x;
  int i = blockIdx.x * 1024 + t;
  int lane = t & 63, wid = t >> 6;
  int v = (i < N_NODES) ? cnt[i] : 0;
  int s = v;
  #pragma unroll
  for (int d = 1; d < 64; d <<= 1) {
    int u = __shfl_up(s, d, 64);
    if (lane >= d) s += u;
  }
  if (lane == 63) wsum[wid] = s;
  __syncthreads();
  if (wid == 0) {
    int ws = (lane < 16) ? wsum[lane] : 0;
    #pragma unroll
    for (int d = 1; d < 16; d <<= 1) {
      int u = __shfl_up(ws, d, 64);
      if (lane >= d) ws += u;
    }
    if (lane < 16) wsum[lane] = ws;
  }
  __syncthreads();
  int excl = s - v + (wid ? wsum[wid - 1] : 0);
  if (i < N_NODES) row[i] = excl;
  if (t == 1023) bsum[blockIdx.x] = wsum[15];
}

__global__ __launch_bounds__(1024) void scan_add_kernel(
    int* __restrict__ row, const int* __restrict__ bsum) {
  __shared__ int soff;
  int t = threadIdx.x;
  if (t < 64) {
    int v = (t < (int)blockIdx.x && t < SCAN_NBLK) ? bsum[t] : 0;
    #pragma unroll
    for (int d = 32; d >= 1; d >>= 1) v += __shfl_down(v, d, 64);
    if (t == 0) soff = v;
  }
  __syncthreads();
  int i = blockIdx.x * 1024 + t;
  if (i < N_NODES) row[i] += soff;
  if (i == 0) row[N_NODES] = N_EDGES;
}

// pass 2: local rank via LDS atomic return; pos = row[d] + P[b][d] + r
__global__ __launch_bounds__(1024) void scatter_pass_kernel(
    const int* __restrict__ ei, const int* __restrict__ row,
    const unsigned* __restrict__ P, int* __restrict__ srt) {
  __shared__ unsigned cnt[NWORDS];   // 100 KB
  int t = threadIdx.x, b = blockIdx.x;
  for (int i = t; i < NWORDS; i += 1024) cnt[i] = 0;
  __syncthreads();
  int base = b * EPB;
  const unsigned* Pb = P + (size_t)b * NWORDS;
  for (int i = t; i < EPB; i += 1024) {
    int s = ei[base + i];
    int d = ei[N_EDGES + base + i];
    int sh = (d & 1) * 16;
    unsigned old = atomicAdd(&cnt[d >> 1], 1u << sh);
    int r = (int)((old >> sh) & 0xFFFFu);
    int p = (int)((Pb[d >> 1] >> sh) & 0xFFFFu);
    srt[row[d] + p + r] = s;
  }
}

// ---------------------------------------------------------------- agg (conv1): from emb table
// 16 lanes/node, bf16x8 (16 B) per lane; 16 nodes per 256-block
__global__ __launch_bounds__(256) void agg_emb_kernel(
    const unsigned short* __restrict__ embb, const int* __restrict__ xidx,
    const int* __restrict__ row, const int* __restrict__ srt,
    unsigned short* __restrict__ xa) {
  int n = blockIdx.x * 16 + (threadIdx.x >> 4);
  int c = threadIdx.x & 15;
  int lo = row[n], hi = row[n + 1];
  bf16x8 sv = *(const bf16x8*)(embb + (size_t)xidx[n] * DIM + c * 8);
  float a[8];
  #pragma unroll
  for (int e = 0; e < 8; ++e) a[e] = bf2f((unsigned short)sv[e]);
  int k = lo;
  for (; k + 4 <= hi; k += 4) {
    int v0 = xidx[srt[k]],     v1 = xidx[srt[k + 1]];
    int v2 = xidx[srt[k + 2]], v3 = xidx[srt[k + 3]];
    bf16x8 w0 = *(const bf16x8*)(embb + (size_t)v0 * DIM + c * 8);
    bf16x8 w1 = *(const bf16x8*)(embb + (size_t)v1 * DIM + c * 8);
    bf16x8 w2 = *(const bf16x8*)(embb + (size_t)v2 * DIM + c * 8);
    bf16x8 w3 = *(const bf16x8*)(embb + (size_t)v3 * DIM + c * 8);
    #pragma unroll
    for (int e = 0; e < 8; ++e)
      a[e] += bf2f((unsigned short)w0[e]) + bf2f((unsigned short)w1[e]) +
              bf2f((unsigned short)w2[e]) + bf2f((unsigned short)w3[e]);
  }
  for (; k < hi; ++k) {
    int v = xidx[srt[k]];
    bf16x8 w = *(const bf16x8*)(embb + (size_t)v * DIM + c * 8);
    #pragma unroll
    for (int e = 0; e < 8; ++e) a[e] += bf2f((unsigned short)w[e]);
  }
  bf16x8 o;
  #pragma unroll
  for (int e = 0; e < 8; ++e) o[e] = (short)f2bf(a[e]);
  *(bf16x8*)(xa + (size_t)n * DIM + c * 8) = o;
}

// ---------------------------------------------------------------- agg (conv2): from node features
__global__ __launch_bounds__(256) void agg_x_kernel(
    const unsigned short* __restrict__ x, const int* __restrict__ row,
    const int* __restrict__ srt, unsigned short* __restrict__ xa) {
  int n = blockIdx.x * 16 + (threadIdx.x >> 4);
  int c = threadIdx.x & 15;
  int lo = row[n], hi = row[n + 1];
  bf16x8 sv = *(const bf16x8*)(x + (size_t)n * DIM + c * 8);
  float a[8];
  #pragma unroll
  for (int e = 0; e < 8; ++e) a[e] = bf2f((unsigned short)sv[e]);
  int k = lo;
  for (; k + 4 <= hi; k += 4) {
    int s0 = srt[k], s1 = srt[k + 1], s2 = srt[k + 2], s3 = srt[k + 3];
    bf16x8 w0 = *(const bf16x8*)(x + (size_t)s0 * DIM + c * 8);
    bf16x8 w1 = *(const bf16x8*)(x + (size_t)s1 * DIM + c * 8);
    bf16x8 w2 = *(const bf16x8*)(x + (size_t)s2 * DIM + c * 8);
    bf16x8 w3 = *(const bf16x8*)(x + (size_t)s3 * DIM + c * 8);
    #pragma unroll
    for (int e = 0; e < 8; ++e)
      a[e] += bf2f((unsigned short)w0[e]) + bf2f((unsigned short)w1[e]) +
              bf2f((unsigned short)w2[e]) + bf2f((unsigned short)w3[e]);
  }
  for (; k < hi; ++k) {
    int s = srt[k];
    bf16x8 w = *(const bf16x8*)(x + (size_t)s * DIM + c * 8);
    #pragma unroll
    for (int e = 0; e < 8; ++e) a[e] += bf2f((unsigned short)w[e]);
  }
  bf16x8 o;
  #pragma unroll
  for (int e = 0; e < 8; ++e) o[e] = (short)f2bf(a[e]);
  *(bf16x8*)(xa + (size_t)n * DIM + c * 8) = o;
}

// ---------------------------------------------------------------- MFMA 2-layer MLP
__global__ __launch_bounds__(256) void mlp_mfma_kernel(
    const unsigned short* __restrict__ xa,
    const float* __restrict__ wa, const float* __restrict__ ba,
    const float* __restrict__ wb, const float* __restrict__ bb,
    unsigned short* __restrict__ xout) {
  __shared__ short Xs[64 * 128];   // 16 KB, 16B-chunk XOR swizzle (chunk ^= row&7)
  __shared__ short Hs[64 * 128];   // 16 KB
  int t = threadIdx.x;
  int lane = t & 63;
  int w = t >> 6;
  int jq = w * 32;
  int l15 = lane & 15;
  int lg = lane >> 4;
  int nbase = blockIdx.x * 64;

  bf16x8 waf[2][4], wbf[2][4];
  #pragma unroll
  for (int jm = 0; jm < 2; ++jm) {
    int jrow = jq + jm * 16 + l15;
    #pragma unroll
    for (int ks = 0; ks < 4; ++ks) {
      int k0 = ks * 32 + lg * 8;
      f32x4 a0 = *(const f32x4*)(wa + jrow * DIM + k0);
      f32x4 a1 = *(const f32x4*)(wa + jrow * DIM + k0 + 4);
      f32x4 c0 = *(const f32x4*)(wb + jrow * DIM + k0);
      f32x4 c1 = *(const f32x4*)(wb + jrow * DIM + k0 + 4);
      bf16x8 fa, fb;
      #pragma unroll
      for (int e = 0; e < 4; ++e) {
        fa[e] = (short)f2bf(a0[e]); fa[4 + e] = (short)f2bf(a1[e]);
        fb[e] = (short)f2bf(c0[e]); fb[4 + e] = (short)f2bf(c1[e]);
      }
      waf[jm][ks] = fa; wbf[jm][ks] = fb;
    }
  }
  f32x4 ba_r[2], bb_r[2];
  #pragma unroll
  for (int jm = 0; jm < 2; ++jm) {
    ba_r[jm] = *(const f32x4*)(ba + jq + jm * 16 + lg * 4);
    bb_r[jm] = *(const f32x4*)(bb + jq + jm * 16 + lg * 4);
  }

  {
    int r = t >> 2;
    int cb = (t & 3) * 4;
    int node = nbase + r;
    #pragma unroll
    for (int i = 0; i < 4; ++i) {
      int chunk = cb + i;
      bf16x8 v = {0, 0, 0, 0, 0, 0, 0, 0};
      if (node < N_NODES)
        v = *(const bf16x8*)(xa + (size_t)node * DIM + chunk * 8);
      *(bf16x8*)&Xs[r * 128 + ((chunk ^ (r & 7)) << 3)] = v;
    }
  }
  __syncthreads();

  #pragma unroll
  for (int nt = 0; nt < 4; ++nt) {
    int rrow = nt * 16 + l15;
    bf16x8 xf[4];
    #pragma unroll
    for (int ks = 0; ks < 4; ++ks) {
      int chunk = ks * 4 + lg;
      xf[ks] = *(const bf16x8*)&Xs[rrow * 128 + ((chunk ^ (rrow & 7)) << 3)];
    }
    #pragma unroll
    for (int jm = 0; jm < 2; ++jm) {
      f32x4 acc = ba_r[jm];
      #pragma unroll
      for (int ks = 0; ks < 4; ++ks)
        acc = __builtin_amdgcn_mfma_f32_16x16x32_bf16(waf[jm][ks], xf[ks], acc, 0, 0, 0);
      int hnode = nt * 16 + l15;
      int cbase = jq + jm * 16 + lg * 4;
      unsigned p0 = (unsigned)f2bf(fmaxf(acc[0], 0.f)) |
                    ((unsigned)f2bf(fmaxf(acc[1], 0.f)) << 16);
      unsigned p1 = (unsigned)f2bf(fmaxf(acc[2], 0.f)) |
                    ((unsigned)f2bf(fmaxf(acc[3], 0.f)) << 16);
      unsigned idx = hnode * 128 + (((cbase >> 3) ^ (hnode & 7)) << 3) + (cbase & 7);
      *(uint2*)&Hs[idx] = make_uint2(p0, p1);
    }
  }
  __syncthreads();

  #pragma unroll
  for (int nt = 0; nt < 4; ++nt) {
    int rrow = nt * 16 + l15;
    bf16x8 hf[4];
    #pragma unroll
    for (int ks = 0; ks < 4; ++ks) {
      int chunk = ks * 4 + lg;
      hf[ks] = *(const bf16x8*)&Hs[rrow * 128 + ((chunk ^ (rrow & 7)) << 3)];
    }
    #pragma unroll
    for (int jm = 0; jm < 2; ++jm) {
      f32x4 acc = bb_r[jm];
      #pragma unroll
      for (int ks = 0; ks < 4; ++ks)
        acc = __builtin_amdgcn_mfma_f32_16x16x32_bf16(wbf[jm][ks], hf[ks], acc, 0, 0, 0);
      int node = nbase + nt * 16 + l15;
      if (node < N_NODES) {
        bf16x4 o;
        #pragma unroll
        for (int e = 0; e < 4; ++e) o[e] = (short)f2bf(fmaxf(acc[e], 0.f));
        *(bf16x4*)(xout + (size_t)node * DIM + jq + jm * 16 + lg * 4) = o;
      }
    }
  }
}

// ---------------------------------------------------------------- mean-pool + FC (row-parallel)
#define PP 132
__global__ __launch_bounds__(256) void pool_fc_kernel(
    const unsigned short* __restrict__ x, const int* __restrict__ batch,
    const float* __restrict__ fcw, const float* __restrict__ fcb,
    float* __restrict__ out) {
  int g = blockIdx.x, t = threadIdx.x;
  __shared__ float part[16 * PP];
  __shared__ float pooled[DIM];
  __shared__ int sbound[2];
  if (t < 2) {
    int target = g + t;
    int lo = 0, hi = N_NODES;
    while (lo < hi) {
      int m = (lo + hi) >> 1;
      if (batch[m] < target) lo = m + 1; else hi = m;
    }
    sbound[t] = lo;
  }
  __syncthreads();
  int lo = sbound[0], hi = sbound[1];
  int r = t >> 4, c = t & 15;
  float acc[8] = {0.f, 0.f, 0.f, 0.f, 0.f, 0.f, 0.f, 0.f};
  for (int nn = lo + r; nn < hi; nn += 16) {
    bf16x8 v = *(const bf16x8*)(x + (size_t)nn * DIM + c * 8);
    #pragma unroll
    for (int e = 0; e < 8; ++e) acc[e] += bf2f((unsigned short)v[e]);
  }
  #pragma unroll
  for (int e = 0; e < 8; ++e) part[r * PP + c * 8 + e] = acc[e];
  __syncthreads();
  if (t < DIM) {
    float s = 0.f;
    #pragma unroll
    for (int rr = 0; rr < 16; ++rr) s += part[rr * PP + t];
    pooled[t] = s / fmaxf((float)(hi - lo), 1.0f);
  }
  __syncthreads();
  if (t < ODIM) {
    float a = fcb[t];
    const float* wr = fcw + (size_t)t * DIM;
    #pragma unroll 8
    for (int h = 0; h < DIM; ++h) a += pooled[h] * wr[h];
    out[(size_t)g * ODIM + t] = a;
  }
}

// ---------------------------------------------------------------- launch
extern "C" void kernel_launch(void* const* d_in, const int* in_sizes, int n_in,
                              void* d_out, int out_size, void* d_ws, size_t ws_size,
                              hipStream_t stream) {
  const float* emb  = (const float*)d_in[0];
  const float* w1a  = (const float*)d_in[1];
  const float* b1a  = (const float*)d_in[2];
  const float* w1b  = (const float*)d_in[3];
  const float* b1b  = (const float*)d_in[4];
  const float* w2a  = (const float*)d_in[5];
  const float* b2a  = (const float*)d_in[6];
  const float* w2b  = (const float*)d_in[7];
  const float* b2b  = (const float*)d_in[8];
  const float* fcw  = (const float*)d_in[9];
  const float* fcb  = (const float*)d_in[10];
  const int*   xidx = (const int*)d_in[11];
  const int*   ei   = (const int*)d_in[12];
  const int*   batch= (const int*)d_in[13];
  float* out = (float*)d_out;

  size_t featb = (size_t)N_NODES * DIM * sizeof(unsigned short);  // 12.8 MB
  char* ws = (char*)d_ws;
  unsigned short* B1 = (unsigned short*)ws;             // xa (conv in)
  unsigned short* B2 = (unsigned short*)(ws + featb);   // conv out
  char* p = ws + 2 * featb;
  unsigned short* embb = (unsigned short*)p;  p += (VOCAB * DIM * 2 + 15) / 16 * 16;
  int* row  = (int*)p;  p += ((N_NODES + 1) * 4 + 15) / 16 * 16;
  int* deg  = (int*)p;  p += (N_NODES * 4 + 15) / 16 * 16;
  int* bsum = (int*)p;  p += (SCAN_NBLK * 4 + 15) / 16 * 16;
  unsigned* H = (unsigned*)p;  p += (size_t)NB * NWORDS * 4;   // 6.4 MB
  unsigned* P = (unsigned*)p;  p += (size_t)NB * NWORDS * 4;   // 6.4 MB
  int* srt  = (int*)p;  // N_EDGES ints (3.2 MB)

  emb2bf_kernel<<<(VOCAB * 16 + 255) / 256, 256, 0, stream>>>(emb, embb);

  // CSR build (by dst): LDS counting sort, zero global atomics
  hist_pass_kernel<<<NB, 1024, 0, stream>>>(ei, H);
  transpose_scan_kernel<<<(NWORDS + 255) / 256, 256, 0, stream>>>(H, P, deg);
  scan_local_kernel<<<SCAN_NBLK, 1024, 0, stream>>>(deg, row, bsum);
  scan_add_kernel<<<SCAN_NBLK, 1024, 0, stream>>>(row, bsum);
  scatter_pass_kernel<<<NB, 1024, 0, stream>>>(ei, row, P, srt);

  // conv1: gather from L2-resident emb table
  agg_emb_kernel<<<N_NODES / 16, 256, 0, stream>>>(embb, xidx, row, srt, B1);
  mlp_mfma_kernel<<<(N_NODES + 63) / 64, 256, 0, stream>>>(B1, w1a, b1a, w1b, b1b, B2);

  // conv2: gather from node features
  agg_x_kernel<<<N_NODES / 16, 256, 0, stream>>>(B2, row, srt, B1);
  mlp_mfma_kernel<<<(N_NODES + 63) / 64, 256, 0, stream>>>(B1, w2a, b2a, w2b, b2b, B2);

  pool_fc_kernel<<<NGRAPH, 256, 0, stream>>>(B2, batch, fcw, fcb, out);
}

// Round 9
// 165.839 us; speedup vs baseline: 2.3875x; 1.0621x over previous
//
#include <hip/hip_runtime.h>

#define N_NODES 50000
#define N_EDGES 800000
#define DIM 128
#define NGRAPH 512
#define ODIM 64
#define VOCAB 500
#define NBKT 391              // ceil(50000/128) coarse dst-buckets (128 nodes each)
#define NB2 128               // edge partitions
#define EPB2 (N_EDGES / NB2)  // 6250
#define CAP 4096              // max edges per bucket staged in LDS (mean 2046)

typedef __attribute__((ext_vector_type(8))) short bf16x8;
typedef __attribute__((ext_vector_type(4))) short bf16x4;
typedef __attribute__((ext_vector_type(4))) float f32x4;

__device__ inline unsigned short f2bf(float f) {
  unsigned u = __builtin_bit_cast(unsigned, f);
  return (unsigned short)((u + 0x7fffu + ((u >> 16) & 1u)) >> 16);
}
__device__ inline float bf2f(unsigned short h) {
  unsigned u = ((unsigned)h) << 16;
  return __builtin_bit_cast(float, u);
}

// ---------------------------------------------------------------- emb f32 -> bf16 (128 KB)
__global__ __launch_bounds__(256) void emb2bf_kernel(
    const float* __restrict__ emb, unsigned short* __restrict__ embb) {
  int i = blockIdx.x * 256 + threadIdx.x;
  if (i >= VOCAB * 16) return;
  const f32x4* src = (const f32x4*)(emb + (size_t)i * 8);
  f32x4 a = src[0], b = src[1];
  bf16x8 o;
  #pragma unroll
  for (int e = 0; e < 4; ++e) {
    o[e] = (short)f2bf(a[e]);
    o[4 + e] = (short)f2bf(b[e]);
  }
  *(bf16x8*)(embb + (size_t)i * 8) = o;
}

// ---------------------------------------------------------------- CSR build: two-level bucket sort
// pass 1: per-partition coarse-bucket histogram
__global__ __launch_bounds__(512) void bkt_hist_kernel(
    const int* __restrict__ ei, unsigned* __restrict__ HB) {
  __shared__ unsigned cnt[NBKT];
  int t = threadIdx.x, b = blockIdx.x;
  for (int i = t; i < NBKT; i += 512) cnt[i] = 0;
  __syncthreads();
  int base = b * EPB2;
  for (int i = t; i < EPB2; i += 512)
    atomicAdd(&cnt[(unsigned)ei[N_EDGES + base + i] >> 7], 1u);
  __syncthreads();
  for (int i = t; i < NBKT; i += 512) HB[(size_t)b * NBKT + i] = cnt[i];
}

// transpose-scan: OFF[b][k] = bktbase[k] + sum_{b'<b} HB[b'][k]; bktbase = excl scan of totals
__global__ __launch_bounds__(512) void bkt_scan_kernel(
    const unsigned* __restrict__ HB, unsigned* __restrict__ OFF,
    int* __restrict__ bktbase, int* __restrict__ row) {
  __shared__ unsigned wsum[8];
  int t = threadIdx.x;
  int lane = t & 63, wid = t >> 6;
  unsigned run = 0;
  if (t < NBKT) {
    for (int b = 0; b < NB2; ++b) {
      unsigned h = HB[(size_t)b * NBKT + t];
      OFF[(size_t)b * NBKT + t] = run;
      run += h;
    }
  }
  unsigned s = run;
  #pragma unroll
  for (int d = 1; d < 64; d <<= 1) {
    unsigned u = __shfl_up(s, d, 64);
    if (lane >= d) s += u;
  }
  if (lane == 63) wsum[wid] = s;
  __syncthreads();
  if (wid == 0) {
    unsigned ws = (lane < 8) ? wsum[lane] : 0;
    #pragma unroll
    for (int d = 1; d < 8; d <<= 1) {
      unsigned u = __shfl_up(ws, d, 64);
      if (lane >= d) ws += u;
    }
    if (lane < 8) wsum[lane] = ws;
  }
  __syncthreads();
  unsigned base = s - run + (wid ? wsum[wid - 1] : 0);
  if (t < NBKT) {
    bktbase[t] = (int)base;
    for (int b = 0; b < NB2; ++b) OFF[(size_t)b * NBKT + t] += base;
  }
  if (t == NBKT - 1) {
    bktbase[NBKT] = (int)(base + run);   // == N_EDGES
    row[N_NODES] = N_EDGES;
  }
}

// pass 2: scatter edges into coarse buckets (packed u32: dloc<<16 | src)
__global__ __launch_bounds__(512) void bkt_scatter_kernel(
    const int* __restrict__ ei, const unsigned* __restrict__ OFF,
    unsigned* __restrict__ eb) {
  __shared__ unsigned cur[NBKT];
  int t = threadIdx.x, b = blockIdx.x;
  for (int i = t; i < NBKT; i += 512) cur[i] = OFF[(size_t)b * NBKT + i];
  __syncthreads();
  int base = b * EPB2;
  for (int i = t; i < EPB2; i += 512) {
    int s = ei[base + i];
    unsigned d = (unsigned)ei[N_EDGES + base + i];
    unsigned pos = atomicAdd(&cur[d >> 7], 1u);
    eb[pos] = ((d & 127u) << 16) | (unsigned)s;
  }
}

// pass 3: per-bucket LDS counting sort -> coalesced srt + row for 128 nodes
__global__ __launch_bounds__(256) void sort_bucket_kernel(
    const unsigned* __restrict__ eb, const int* __restrict__ bktbase,
    int* __restrict__ srt, int* __restrict__ row) {
  __shared__ unsigned stage[CAP];
  __shared__ unsigned short sorted[CAP];
  __shared__ unsigned hist[128], excl[128], cur[128];
  __shared__ unsigned wtot;
  int t = threadIdx.x, bkt = blockIdx.x;
  int base = bktbase[bkt], end = bktbase[bkt + 1];
  int cnt = end - base;
  if (cnt > CAP) cnt = CAP;   // statistically impossible; guards LDS
  if (t < 128) hist[t] = 0;
  __syncthreads();
  for (int i = t; i < cnt; i += 256) {
    unsigned e = eb[base + i];
    stage[i] = e;
    atomicAdd(&hist[e >> 16], 1u);
  }
  __syncthreads();
  if (t < 128) {                       // exclusive scan of 128 counters (2 waves)
    int lane = t & 63, w = t >> 6;
    unsigned v = hist[t], s = v;
    #pragma unroll
    for (int d = 1; d < 64; d <<= 1) {
      unsigned u = __shfl_up(s, d, 64);
      if (lane >= d) s += u;
    }
    if (t == 63) wtot = s;
    excl[t] = s - v;
    (void)w;
  }
  __syncthreads();
  if (t < 128) {
    unsigned e0 = excl[t] + (t >= 64 ? wtot : 0u);
    excl[t] = e0;
    cur[t] = e0;
    int n = bkt * 128 + t;
    if (n < N_NODES) row[n] = base + (int)e0;
  }
  __syncthreads();
  for (int i = t; i < cnt; i += 256) {
    unsigned e = stage[i];
    unsigned r = atomicAdd(&cur[e >> 16], 1u);
    sorted[r] = (unsigned short)(e & 0xFFFFu);
  }
  __syncthreads();
  for (int i = t; i < cnt; i += 256) srt[base + i] = (int)sorted[i];
}

// ---------------------------------------------------------------- agg (conv1): from emb table
// 16 lanes/node, bf16x8 (16 B) per lane; 16 nodes per 256-block
__global__ __launch_bounds__(256) void agg_emb_kernel(
    const unsigned short* __restrict__ embb, const int* __restrict__ xidx,
    const int* __restrict__ row, const int* __restrict__ srt,
    unsigned short* __restrict__ xa) {
  int n = blockIdx.x * 16 + (threadIdx.x >> 4);
  int c = threadIdx.x & 15;
  int lo = row[n], hi = row[n + 1];
  bf16x8 sv = *(const bf16x8*)(embb + (size_t)xidx[n] * DIM + c * 8);
  float a[8];
  #pragma unroll
  for (int e = 0; e < 8; ++e) a[e] = bf2f((unsigned short)sv[e]);
  int k = lo;
  for (; k + 4 <= hi; k += 4) {
    int v0 = xidx[srt[k]],     v1 = xidx[srt[k + 1]];
    int v2 = xidx[srt[k + 2]], v3 = xidx[srt[k + 3]];
    bf16x8 w0 = *(const bf16x8*)(embb + (size_t)v0 * DIM + c * 8);
    bf16x8 w1 = *(const bf16x8*)(embb + (size_t)v1 * DIM + c * 8);
    bf16x8 w2 = *(const bf16x8*)(embb + (size_t)v2 * DIM + c * 8);
    bf16x8 w3 = *(const bf16x8*)(embb + (size_t)v3 * DIM + c * 8);
    #pragma unroll
    for (int e = 0; e < 8; ++e)
      a[e] += bf2f((unsigned short)w0[e]) + bf2f((unsigned short)w1[e]) +
              bf2f((unsigned short)w2[e]) + bf2f((unsigned short)w3[e]);
  }
  for (; k < hi; ++k) {
    int v = xidx[srt[k]];
    bf16x8 w = *(const bf16x8*)(embb + (size_t)v * DIM + c * 8);
    #pragma unroll
    for (int e = 0; e < 8; ++e) a[e] += bf2f((unsigned short)w[e]);
  }
  bf16x8 o;
  #pragma unroll
  for (int e = 0; e < 8; ++e) o[e] = (short)f2bf(a[e]);
  *(bf16x8*)(xa + (size_t)n * DIM + c * 8) = o;
}

// ---------------------------------------------------------------- agg (conv2): from node features
__global__ __launch_bounds__(256) void agg_x_kernel(
    const unsigned short* __restrict__ x, const int* __restrict__ row,
    const int* __restrict__ srt, unsigned short* __restrict__ xa) {
  int n = blockIdx.x * 16 + (threadIdx.x >> 4);
  int c = threadIdx.x & 15;
  int lo = row[n], hi = row[n + 1];
  bf16x8 sv = *(const bf16x8*)(x + (size_t)n * DIM + c * 8);
  float a[8];
  #pragma unroll
  for (int e = 0; e < 8; ++e) a[e] = bf2f((unsigned short)sv[e]);
  int k = lo;
  for (; k + 4 <= hi; k += 4) {
    int s0 = srt[k], s1 = srt[k + 1], s2 = srt[k + 2], s3 = srt[k + 3];
    bf16x8 w0 = *(const bf16x8*)(x + (size_t)s0 * DIM + c * 8);
    bf16x8 w1 = *(const bf16x8*)(x + (size_t)s1 * DIM + c * 8);
    bf16x8 w2 = *(const bf16x8*)(x + (size_t)s2 * DIM + c * 8);
    bf16x8 w3 = *(const bf16x8*)(x + (size_t)s3 * DIM + c * 8);
    #pragma unroll
    for (int e = 0; e < 8; ++e)
      a[e] += bf2f((unsigned short)w0[e]) + bf2f((unsigned short)w1[e]) +
              bf2f((unsigned short)w2[e]) + bf2f((unsigned short)w3[e]);
  }
  for (; k < hi; ++k) {
    int s = srt[k];
    bf16x8 w = *(const bf16x8*)(x + (size_t)s * DIM + c * 8);
    #pragma unroll
    for (int e = 0; e < 8; ++e) a[e] += bf2f((unsigned short)w[e]);
  }
  bf16x8 o;
  #pragma unroll
  for (int e = 0; e < 8; ++e) o[e] = (short)f2bf(a[e]);
  *(bf16x8*)(xa + (size_t)n * DIM + c * 8) = o;
}

// ---------------------------------------------------------------- MFMA 2-layer MLP
__global__ __launch_bounds__(256) void mlp_mfma_kernel(
    const unsigned short* __restrict__ xa,
    const float* __restrict__ wa, const float* __restrict__ ba,
    const float* __restrict__ wb, const float* __restrict__ bb,
    unsigned short* __restrict__ xout) {
  __shared__ short Xs[64 * 128];   // 16 KB, 16B-chunk XOR swizzle (chunk ^= row&7)
  __shared__ short Hs[64 * 128];   // 16 KB
  int t = threadIdx.x;
  int lane = t & 63;
  int w = t >> 6;
  int jq = w * 32;
  int l15 = lane & 15;
  int lg = lane >> 4;
  int nbase = blockIdx.x * 64;

  bf16x8 waf[2][4], wbf[2][4];
  #pragma unroll
  for (int jm = 0; jm < 2; ++jm) {
    int jrow = jq + jm * 16 + l15;
    #pragma unroll
    for (int ks = 0; ks < 4; ++ks) {
      int k0 = ks * 32 + lg * 8;
      f32x4 a0 = *(const f32x4*)(wa + jrow * DIM + k0);
      f32x4 a1 = *(const f32x4*)(wa + jrow * DIM + k0 + 4);
      f32x4 c0 = *(const f32x4*)(wb + jrow * DIM + k0);
      f32x4 c1 = *(const f32x4*)(wb + jrow * DIM + k0 + 4);
      bf16x8 fa, fb;
      #pragma unroll
      for (int e = 0; e < 4; ++e) {
        fa[e] = (short)f2bf(a0[e]); fa[4 + e] = (short)f2bf(a1[e]);
        fb[e] = (short)f2bf(c0[e]); fb[4 + e] = (short)f2bf(c1[e]);
      }
      waf[jm][ks] = fa; wbf[jm][ks] = fb;
    }
  }
  f32x4 ba_r[2], bb_r[2];
  #pragma unroll
  for (int jm = 0; jm < 2; ++jm) {
    ba_r[jm] = *(const f32x4*)(ba + jq + jm * 16 + lg * 4);
    bb_r[jm] = *(const f32x4*)(bb + jq + jm * 16 + lg * 4);
  }

  {
    int r = t >> 2;
    int cb = (t & 3) * 4;
    int node = nbase + r;
    #pragma unroll
    for (int i = 0; i < 4; ++i) {
      int chunk = cb + i;
      bf16x8 v = {0, 0, 0, 0, 0, 0, 0, 0};
      if (node < N_NODES)
        v = *(const bf16x8*)(xa + (size_t)node * DIM + chunk * 8);
      *(bf16x8*)&Xs[r * 128 + ((chunk ^ (r & 7)) << 3)] = v;
    }
  }
  __syncthreads();

  #pragma unroll
  for (int nt = 0; nt < 4; ++nt) {
    int rrow = nt * 16 + l15;
    bf16x8 xf[4];
    #pragma unroll
    for (int ks = 0; ks < 4; ++ks) {
      int chunk = ks * 4 + lg;
      xf[ks] = *(const bf16x8*)&Xs[rrow * 128 + ((chunk ^ (rrow & 7)) << 3)];
    }
    #pragma unroll
    for (int jm = 0; jm < 2; ++jm) {
      f32x4 acc = ba_r[jm];
      #pragma unroll
      for (int ks = 0; ks < 4; ++ks)
        acc = __builtin_amdgcn_mfma_f32_16x16x32_bf16(waf[jm][ks], xf[ks], acc, 0, 0, 0);
      int hnode = nt * 16 + l15;
      int cbase = jq + jm * 16 + lg * 4;
      unsigned p0 = (unsigned)f2bf(fmaxf(acc[0], 0.f)) |
                    ((unsigned)f2bf(fmaxf(acc[1], 0.f)) << 16);
      unsigned p1 = (unsigned)f2bf(fmaxf(acc[2], 0.f)) |
                    ((unsigned)f2bf(fmaxf(acc[3], 0.f)) << 16);
      unsigned idx = hnode * 128 + (((cbase >> 3) ^ (hnode & 7)) << 3) + (cbase & 7);
      *(uint2*)&Hs[idx] = make_uint2(p0, p1);
    }
  }
  __syncthreads();

  #pragma unroll
  for (int nt = 0; nt < 4; ++nt) {
    int rrow = nt * 16 + l15;
    bf16x8 hf[4];
    #pragma unroll
    for (int ks = 0; ks < 4; ++ks) {
      int chunk = ks * 4 + lg;
      hf[ks] = *(const bf16x8*)&Hs[rrow * 128 + ((chunk ^ (rrow & 7)) << 3)];
    }
    #pragma unroll
    for (int jm = 0; jm < 2; ++jm) {
      f32x4 acc = bb_r[jm];
      #pragma unroll
      for (int ks = 0; ks < 4; ++ks)
        acc = __builtin_amdgcn_mfma_f32_16x16x32_bf16(wbf[jm][ks], hf[ks], acc, 0, 0, 0);
      int node = nbase + nt * 16 + l15;
      if (node < N_NODES) {
        bf16x4 o;
        #pragma unroll
        for (int e = 0; e < 4; ++e) o[e] = (short)f2bf(fmaxf(acc[e], 0.f));
        *(bf16x4*)(xout + (size_t)node * DIM + jq + jm * 16 + lg * 4) = o;
      }
    }
  }
}

// ---------------------------------------------------------------- mean-pool + FC (row-parallel)
#define PP 132
__global__ __launch_bounds__(256) void pool_fc_kernel(
    const unsigned short* __restrict__ x, const int* __restrict__ batch,
    const float* __restrict__ fcw, const float* __restrict__ fcb,
    float* __restrict__ out) {
  int g = blockIdx.x, t = threadIdx.x;
  __shared__ float part[16 * PP];
  __shared__ float pooled[DIM];
  __shared__ int sbound[2];
  if (t < 2) {
    int target = g + t;
    int lo = 0, hi = N_NODES;
    while (lo < hi) {
      int m = (lo + hi) >> 1;
      if (batch[m] < target) lo = m + 1; else hi = m;
    }
    sbound[t] = lo;
  }
  __syncthreads();
  int lo = sbound[0], hi = sbound[1];
  int r = t >> 4, c = t & 15;
  float acc[8] = {0.f, 0.f, 0.f, 0.f, 0.f, 0.f, 0.f, 0.f};
  for (int nn = lo + r; nn < hi; nn += 16) {
    bf16x8 v = *(const bf16x8*)(x + (size_t)nn * DIM + c * 8);
    #pragma unroll
    for (int e = 0; e < 8; ++e) acc[e] += bf2f((unsigned short)v[e]);
  }
  #pragma unroll
  for (int e = 0; e < 8; ++e) part[r * PP + c * 8 + e] = acc[e];
  __syncthreads();
  if (t < DIM) {
    float s = 0.f;
    #pragma unroll
    for (int rr = 0; rr < 16; ++rr) s += part[rr * PP + t];
    pooled[t] = s / fmaxf((float)(hi - lo), 1.0f);
  }
  __syncthreads();
  if (t < ODIM) {
    float a = fcb[t];
    const float* wr = fcw + (size_t)t * DIM;
    #pragma unroll 8
    for (int h = 0; h < DIM; ++h) a += pooled[h] * wr[h];
    out[(size_t)g * ODIM + t] = a;
  }
}

// ---------------------------------------------------------------- launch
extern "C" void kernel_launch(void* const* d_in, const int* in_sizes, int n_in,
                              void* d_out, int out_size, void* d_ws, size_t ws_size,
                              hipStream_t stream) {
  const float* emb  = (const float*)d_in[0];
  const float* w1a  = (const float*)d_in[1];
  const float* b1a  = (const float*)d_in[2];
  const float* w1b  = (const float*)d_in[3];
  const float* b1b  = (const float*)d_in[4];
  const float* w2a  = (const float*)d_in[5];
  const float* b2a  = (const float*)d_in[6];
  const float* w2b  = (const float*)d_in[7];
  const float* b2b  = (const float*)d_in[8];
  const float* fcw  = (const float*)d_in[9];
  const float* fcb  = (const float*)d_in[10];
  const int*   xidx = (const int*)d_in[11];
  const int*   ei   = (const int*)d_in[12];
  const int*   batch= (const int*)d_in[13];
  float* out = (float*)d_out;

  size_t featb = (size_t)N_NODES * DIM * sizeof(unsigned short);  // 12.8 MB
  char* ws = (char*)d_ws;
  unsigned short* B1 = (unsigned short*)ws;             // xa (conv in)
  unsigned short* B2 = (unsigned short*)(ws + featb);   // conv out
  char* p = ws + 2 * featb;
  unsigned short* embb = (unsigned short*)p;  p += (VOCAB * DIM * 2 + 15) / 16 * 16;
  int* row  = (int*)p;      p += ((N_NODES + 1) * 4 + 15) / 16 * 16;
  int* bktbase = (int*)p;   p += ((NBKT + 1) * 4 + 15) / 16 * 16;
  unsigned* HB  = (unsigned*)p;  p += (size_t)NB2 * NBKT * 4;    // 200 KB
  unsigned* OFF = (unsigned*)p;  p += (size_t)NB2 * NBKT * 4;    // 200 KB
  unsigned* eb  = (unsigned*)p;  p += (size_t)N_EDGES * 4;       // 3.2 MB
  int* srt  = (int*)p;      // N_EDGES ints (3.2 MB)

  emb2bf_kernel<<<(VOCAB * 16 + 255) / 256, 256, 0, stream>>>(emb, embb);

  // CSR build: bucket-partition -> per-bucket LDS counting sort (coalesced srt writes)
  bkt_hist_kernel<<<NB2, 512, 0, stream>>>(ei, HB);
  bkt_scan_kernel<<<1, 512, 0, stream>>>(HB, OFF, bktbase, row);
  bkt_scatter_kernel<<<NB2, 512, 0, stream>>>(ei, OFF, eb);
  sort_bucket_kernel<<<NBKT, 256, 0, stream>>>(eb, bktbase, srt, row);

  // conv1: gather from L2-resident emb table
  agg_emb_kernel<<<N_NODES / 16, 256, 0, stream>>>(embb, xidx, row, srt, B1);
  mlp_mfma_kernel<<<(N_NODES + 63) / 64, 256, 0, stream>>>(B1, w1a, b1a, w1b, b1b, B2);

  // conv2: gather from node features
  agg_x_kernel<<<N_NODES / 16, 256, 0, stream>>>(B2, row, srt, B1);
  mlp_mfma_kernel<<<(N_NODES + 63) / 64, 256, 0, stream>>>(B1, w2a, b2a, w2b, b2b, B2);

  pool_fc_kernel<<<NGRAPH, 256, 0, stream>>>(B2, batch, fcw, fcb, out);
}

// Round 10
// 134.585 us; speedup vs baseline: 2.9419x; 1.2322x over previous
//
#include <hip/hip_runtime.h>

#define N_NODES 50000
#define N_EDGES 800000
#define DIM 128
#define NGRAPH 512
#define ODIM 64
#define VOCAB 500
#define NBKT 391              // ceil(50000/128) coarse dst-buckets (128 nodes each)
#define NB2 128               // edge partitions
#define EPB2 (N_EDGES / NB2)  // 6250
#define CAP 4096              // max edges per bucket staged in LDS (mean 2046)

typedef __attribute__((ext_vector_type(8))) short bf16x8;
typedef __attribute__((ext_vector_type(4))) short bf16x4;
typedef __attribute__((ext_vector_type(4))) float f32x4;

__device__ inline unsigned short f2bf(float f) {
  unsigned u = __builtin_bit_cast(unsigned, f);
  return (unsigned short)((u + 0x7fffu + ((u >> 16) & 1u)) >> 16);
}
__device__ inline float bf2f(unsigned short h) {
  unsigned u = ((unsigned)h) << 16;
  return __builtin_bit_cast(float, u);
}

// ---------------------------------------------------------------- emb f32 -> bf16 (128 KB)
__global__ __launch_bounds__(256) void emb2bf_kernel(
    const float* __restrict__ emb, unsigned short* __restrict__ embb) {
  int i = blockIdx.x * 256 + threadIdx.x;
  if (i >= VOCAB * 16) return;
  const f32x4* src = (const f32x4*)(emb + (size_t)i * 8);
  f32x4 a = src[0], b = src[1];
  bf16x8 o;
  #pragma unroll
  for (int e = 0; e < 4; ++e) {
    o[e] = (short)f2bf(a[e]);
    o[4 + e] = (short)f2bf(b[e]);
  }
  *(bf16x8*)(embb + (size_t)i * 8) = o;
}

// ---------------------------------------------------------------- weights f32 -> bf16 (one-time)
__global__ __launch_bounds__(256) void w2bf_kernel(
    const float* __restrict__ w1a, const float* __restrict__ w1b,
    const float* __restrict__ w2a, const float* __restrict__ w2b,
    unsigned short* __restrict__ wbf) {
  int u = blockIdx.x * 256 + threadIdx.x;      // one bf16x8 unit (8 elems)
  if (u >= 4 * 2048) return;                   // 4 matrices x 16384 elems / 8
  int m = u >> 11, loc = u & 2047;
  const float* src = (m == 0) ? w1a : (m == 1) ? w1b : (m == 2) ? w2a : w2b;
  const f32x4* sp = (const f32x4*)(src + (size_t)loc * 8);
  f32x4 a = sp[0], b = sp[1];
  bf16x8 o;
  #pragma unroll
  for (int e = 0; e < 4; ++e) {
    o[e] = (short)f2bf(a[e]);
    o[4 + e] = (short)f2bf(b[e]);
  }
  *(bf16x8*)(wbf + (size_t)u * 8) = o;
}

// ---------------------------------------------------------------- CSR build: two-level bucket sort
// pass 1: per-partition coarse-bucket histogram
__global__ __launch_bounds__(512) void bkt_hist_kernel(
    const int* __restrict__ ei, unsigned* __restrict__ HB) {
  __shared__ unsigned cnt[NBKT];
  int t = threadIdx.x, b = blockIdx.x;
  for (int i = t; i < NBKT; i += 512) cnt[i] = 0;
  __syncthreads();
  int base = b * EPB2;
  for (int i = t; i < EPB2; i += 512)
    atomicAdd(&cnt[(unsigned)ei[N_EDGES + base + i] >> 7], 1u);
  __syncthreads();
  for (int i = t; i < NBKT; i += 512) HB[(size_t)b * NBKT + i] = cnt[i];
}

// parallel column scan: per bucket k, OFF[b][k] = sum_{b'<b} HB[b'][k] (relative); tot[k] = total
__global__ __launch_bounds__(128) void col_scan_kernel(
    const unsigned* __restrict__ HB, unsigned* __restrict__ OFF,
    unsigned* __restrict__ tot) {
  __shared__ unsigned w0s;
  int k = blockIdx.x, t = threadIdx.x;      // t = partition index (NB2=128)
  int lane = t & 63, wid = t >> 6;
  unsigned v = HB[(size_t)t * NBKT + k];
  unsigned s = v;
  #pragma unroll
  for (int d = 1; d < 64; d <<= 1) {
    unsigned u = __shfl_up(s, d, 64);
    if (lane >= d) s += u;
  }
  if (wid == 0 && lane == 63) w0s = s;
  __syncthreads();
  unsigned excl = s - v + (wid ? w0s : 0u);
  OFF[(size_t)t * NBKT + k] = excl;
  if (t == 127) tot[k] = excl + v;
}

// tiny scan of 391 bucket totals -> bktbase
__global__ __launch_bounds__(512) void base_scan_kernel(
    const unsigned* __restrict__ tot, int* __restrict__ bktbase,
    int* __restrict__ row) {
  __shared__ unsigned wsum[8];
  int t = threadIdx.x;
  int lane = t & 63, wid = t >> 6;
  unsigned v = (t < NBKT) ? tot[t] : 0u;
  unsigned s = v;
  #pragma unroll
  for (int d = 1; d < 64; d <<= 1) {
    unsigned u = __shfl_up(s, d, 64);
    if (lane >= d) s += u;
  }
  if (lane == 63) wsum[wid] = s;
  __syncthreads();
  if (wid == 0) {
    unsigned ws = (lane < 8) ? wsum[lane] : 0u;
    #pragma unroll
    for (int d = 1; d < 8; d <<= 1) {
      unsigned u = __shfl_up(ws, d, 64);
      if (lane >= d) ws += u;
    }
    if (lane < 8) wsum[lane] = ws;
  }
  __syncthreads();
  unsigned excl = s - v + (wid ? wsum[wid - 1] : 0u);
  if (t < NBKT) bktbase[t] = (int)excl;
  if (t == NBKT - 1) {
    bktbase[NBKT] = (int)(excl + v);   // == N_EDGES
    row[N_NODES] = N_EDGES;
  }
}

// pass 2: scatter edges into coarse buckets (packed u32: dloc<<16 | src)
__global__ __launch_bounds__(512) void bkt_scatter_kernel(
    const int* __restrict__ ei, const unsigned* __restrict__ OFF,
    const int* __restrict__ bktbase, unsigned* __restrict__ eb) {
  __shared__ unsigned cur[NBKT];
  int t = threadIdx.x, b = blockIdx.x;
  for (int i = t; i < NBKT; i += 512)
    cur[i] = OFF[(size_t)b * NBKT + i] + (unsigned)bktbase[i];
  __syncthreads();
  int base = b * EPB2;
  for (int i = t; i < EPB2; i += 512) {
    int s = ei[base + i];
    unsigned d = (unsigned)ei[N_EDGES + base + i];
    unsigned pos = atomicAdd(&cur[d >> 7], 1u);
    eb[pos] = ((d & 127u) << 16) | (unsigned)s;
  }
}

// pass 3: per-bucket LDS counting sort -> coalesced srt + row for 128 nodes
__global__ __launch_bounds__(256) void sort_bucket_kernel(
    const unsigned* __restrict__ eb, const int* __restrict__ bktbase,
    int* __restrict__ srt, int* __restrict__ row) {
  __shared__ unsigned stage[CAP];
  __shared__ unsigned short sorted[CAP];
  __shared__ unsigned hist[128], excl[128], cur[128];
  __shared__ unsigned wtot;
  int t = threadIdx.x, bkt = blockIdx.x;
  int base = bktbase[bkt], end = bktbase[bkt + 1];
  int cnt = end - base;
  if (cnt > CAP) cnt = CAP;   // statistically impossible; guards LDS
  if (t < 128) hist[t] = 0;
  __syncthreads();
  for (int i = t; i < cnt; i += 256) {
    unsigned e = eb[base + i];
    stage[i] = e;
    atomicAdd(&hist[e >> 16], 1u);
  }
  __syncthreads();
  if (t < 128) {
    int lane = t & 63;
    unsigned v = hist[t], s = v;
    #pragma unroll
    for (int d = 1; d < 64; d <<= 1) {
      unsigned u = __shfl_up(s, d, 64);
      if (lane >= d) s += u;
    }
    if (t == 63) wtot = s;
    excl[t] = s - v;
  }
  __syncthreads();
  if (t < 128) {
    unsigned e0 = excl[t] + (t >= 64 ? wtot : 0u);
    cur[t] = e0;
    int n = bkt * 128 + t;
    if (n < N_NODES) row[n] = base + (int)e0;
  }
  __syncthreads();
  for (int i = t; i < cnt; i += 256) {
    unsigned e = stage[i];
    unsigned r = atomicAdd(&cur[e >> 16], 1u);
    sorted[r] = (unsigned short)(e & 0xFFFFu);
  }
  __syncthreads();
  for (int i = t; i < cnt; i += 256) srt[base + i] = (int)sorted[i];
}

// ---------------------------------------------------------------- agg (conv1): from emb table
// 16 lanes/node, bf16x8 (16 B) per lane; 16 nodes per 256-block; 8-deep gather unroll
__global__ __launch_bounds__(256) void agg_emb_kernel(
    const unsigned short* __restrict__ embb, const int* __restrict__ xidx,
    const int* __restrict__ row, const int* __restrict__ srt,
    unsigned short* __restrict__ xa) {
  int n = blockIdx.x * 16 + (threadIdx.x >> 4);
  int c = threadIdx.x & 15;
  int lo = row[n], hi = row[n + 1];
  bf16x8 sv = *(const bf16x8*)(embb + (size_t)xidx[n] * DIM + c * 8);
  float a[8];
  #pragma unroll
  for (int e = 0; e < 8; ++e) a[e] = bf2f((unsigned short)sv[e]);
  int k = lo;
  for (; k + 8 <= hi; k += 8) {
    bf16x8 w[8];
    #pragma unroll
    for (int q = 0; q < 8; ++q)
      w[q] = *(const bf16x8*)(embb + (size_t)xidx[srt[k + q]] * DIM + c * 8);
    #pragma unroll
    for (int q = 0; q < 8; ++q)
      #pragma unroll
      for (int e = 0; e < 8; ++e) a[e] += bf2f((unsigned short)w[q][e]);
  }
  for (; k + 2 <= hi; k += 2) {
    bf16x8 w0 = *(const bf16x8*)(embb + (size_t)xidx[srt[k]] * DIM + c * 8);
    bf16x8 w1 = *(const bf16x8*)(embb + (size_t)xidx[srt[k + 1]] * DIM + c * 8);
    #pragma unroll
    for (int e = 0; e < 8; ++e)
      a[e] += bf2f((unsigned short)w0[e]) + bf2f((unsigned short)w1[e]);
  }
  if (k < hi) {
    bf16x8 w = *(const bf16x8*)(embb + (size_t)xidx[srt[k]] * DIM + c * 8);
    #pragma unroll
    for (int e = 0; e < 8; ++e) a[e] += bf2f((unsigned short)w[e]);
  }
  bf16x8 o;
  #pragma unroll
  for (int e = 0; e < 8; ++e) o[e] = (short)f2bf(a[e]);
  *(bf16x8*)(xa + (size_t)n * DIM + c * 8) = o;
}

// ---------------------------------------------------------------- agg (conv2): from node features
__global__ __launch_bounds__(256) void agg_x_kernel(
    const unsigned short* __restrict__ x, const int* __restrict__ row,
    const int* __restrict__ srt, unsigned short* __restrict__ xa) {
  int n = blockIdx.x * 16 + (threadIdx.x >> 4);
  int c = threadIdx.x & 15;
  int lo = row[n], hi = row[n + 1];
  bf16x8 sv = *(const bf16x8*)(x + (size_t)n * DIM + c * 8);
  float a[8];
  #pragma unroll
  for (int e = 0; e < 8; ++e) a[e] = bf2f((unsigned short)sv[e]);
  int k = lo;
  for (; k + 8 <= hi; k += 8) {
    bf16x8 w[8];
    #pragma unroll
    for (int q = 0; q < 8; ++q)
      w[q] = *(const bf16x8*)(x + (size_t)srt[k + q] * DIM + c * 8);
    #pragma unroll
    for (int q = 0; q < 8; ++q)
      #pragma unroll
      for (int e = 0; e < 8; ++e) a[e] += bf2f((unsigned short)w[q][e]);
  }
  for (; k + 2 <= hi; k += 2) {
    bf16x8 w0 = *(const bf16x8*)(x + (size_t)srt[k] * DIM + c * 8);
    bf16x8 w1 = *(const bf16x8*)(x + (size_t)srt[k + 1] * DIM + c * 8);
    #pragma unroll
    for (int e = 0; e < 8; ++e)
      a[e] += bf2f((unsigned short)w0[e]) + bf2f((unsigned short)w1[e]);
  }
  if (k < hi) {
    bf16x8 w = *(const bf16x8*)(x + (size_t)srt[k] * DIM + c * 8);
    #pragma unroll
    for (int e = 0; e < 8; ++e) a[e] += bf2f((unsigned short)w[e]);
  }
  bf16x8 o;
  #pragma unroll
  for (int e = 0; e < 8; ++e) o[e] = (short)f2bf(a[e]);
  *(bf16x8*)(xa + (size_t)n * DIM + c * 8) = o;
}

// ---------------------------------------------------------------- MFMA 2-layer MLP (bf16 weights)
__global__ __launch_bounds__(256) void mlp_mfma_kernel(
    const unsigned short* __restrict__ xa,
    const unsigned short* __restrict__ wabf, const float* __restrict__ ba,
    const unsigned short* __restrict__ wbbf, const float* __restrict__ bb,
    unsigned short* __restrict__ xout) {
  __shared__ short Xs[64 * 128];   // 16 KB, 16B-chunk XOR swizzle (chunk ^= row&7)
  __shared__ short Hs[64 * 128];   // 16 KB
  int t = threadIdx.x;
  int lane = t & 63;
  int w = t >> 6;
  int jq = w * 32;
  int l15 = lane & 15;
  int lg = lane >> 4;
  int nbase = blockIdx.x * 64;

  // A-operand fragments: single 16B bf16 load each (pre-converted weights)
  bf16x8 waf[2][4], wbf[2][4];
  #pragma unroll
  for (int jm = 0; jm < 2; ++jm) {
    int jrow = jq + jm * 16 + l15;
    #pragma unroll
    for (int ks = 0; ks < 4; ++ks) {
      int k0 = ks * 32 + lg * 8;
      waf[jm][ks] = *(const bf16x8*)(wabf + (size_t)jrow * DIM + k0);
      wbf[jm][ks] = *(const bf16x8*)(wbbf + (size_t)jrow * DIM + k0);
    }
  }
  f32x4 ba_r[2], bb_r[2];
  #pragma unroll
  for (int jm = 0; jm < 2; ++jm) {
    ba_r[jm] = *(const f32x4*)(ba + jq + jm * 16 + lg * 4);
    bb_r[jm] = *(const f32x4*)(bb + jq + jm * 16 + lg * 4);
  }

  {
    int r = t >> 2;
    int cb = (t & 3) * 4;
    int node = nbase + r;
    #pragma unroll
    for (int i = 0; i < 4; ++i) {
      int chunk = cb + i;
      bf16x8 v = {0, 0, 0, 0, 0, 0, 0, 0};
      if (node < N_NODES)
        v = *(const bf16x8*)(xa + (size_t)node * DIM + chunk * 8);
      *(bf16x8*)&Xs[r * 128 + ((chunk ^ (r & 7)) << 3)] = v;
    }
  }
  __syncthreads();

  #pragma unroll
  for (int nt = 0; nt < 4; ++nt) {
    int rrow = nt * 16 + l15;
    bf16x8 xf[4];
    #pragma unroll
    for (int ks = 0; ks < 4; ++ks) {
      int chunk = ks * 4 + lg;
      xf[ks] = *(const bf16x8*)&Xs[rrow * 128 + ((chunk ^ (rrow & 7)) << 3)];
    }
    #pragma unroll
    for (int jm = 0; jm < 2; ++jm) {
      f32x4 acc = ba_r[jm];
      #pragma unroll
      for (int ks = 0; ks < 4; ++ks)
        acc = __builtin_amdgcn_mfma_f32_16x16x32_bf16(waf[jm][ks], xf[ks], acc, 0, 0, 0);
      int hnode = nt * 16 + l15;
      int cbase = jq + jm * 16 + lg * 4;
      unsigned p0 = (unsigned)f2bf(fmaxf(acc[0], 0.f)) |
                    ((unsigned)f2bf(fmaxf(acc[1], 0.f)) << 16);
      unsigned p1 = (unsigned)f2bf(fmaxf(acc[2], 0.f)) |
                    ((unsigned)f2bf(fmaxf(acc[3], 0.f)) << 16);
      unsigned idx = hnode * 128 + (((cbase >> 3) ^ (hnode & 7)) << 3) + (cbase & 7);
      *(uint2*)&Hs[idx] = make_uint2(p0, p1);
    }
  }
  __syncthreads();

  #pragma unroll
  for (int nt = 0; nt < 4; ++nt) {
    int rrow = nt * 16 + l15;
    bf16x8 hf[4];
    #pragma unroll
    for (int ks = 0; ks < 4; ++ks) {
      int chunk = ks * 4 + lg;
      hf[ks] = *(const bf16x8*)&Hs[rrow * 128 + ((chunk ^ (rrow & 7)) << 3)];
    }
    #pragma unroll
    for (int jm = 0; jm < 2; ++jm) {
      f32x4 acc = bb_r[jm];
      #pragma unroll
      for (int ks = 0; ks < 4; ++ks)
        acc = __builtin_amdgcn_mfma_f32_16x16x32_bf16(wbf[jm][ks], hf[ks], acc, 0, 0, 0);
      int node = nbase + nt * 16 + l15;
      if (node < N_NODES) {
        bf16x4 o;
        #pragma unroll
        for (int e = 0; e < 4; ++e) o[e] = (short)f2bf(fmaxf(acc[e], 0.f));
        *(bf16x4*)(xout + (size_t)node * DIM + jq + jm * 16 + lg * 4) = o;
      }
    }
  }
}

// ---------------------------------------------------------------- mean-pool + FC (row-parallel)
#define PP 132
__global__ __launch_bounds__(256) void pool_fc_kernel(
    const unsigned short* __restrict__ x, const int* __restrict__ batch,
    const float* __restrict__ fcw, const float* __restrict__ fcb,
    float* __restrict__ out) {
  int g = blockIdx.x, t = threadIdx.x;
  __shared__ float part[16 * PP];
  __shared__ float pooled[DIM];
  __shared__ int sbound[2];
  if (t < 2) {
    int target = g + t;
    int lo = 0, hi = N_NODES;
    while (lo < hi) {
      int m = (lo + hi) >> 1;
      if (batch[m] < target) lo = m + 1; else hi = m;
    }
    sbound[t] = lo;
  }
  __syncthreads();
  int lo = sbound[0], hi = sbound[1];
  int r = t >> 4, c = t & 15;
  float acc[8] = {0.f, 0.f, 0.f, 0.f, 0.f, 0.f, 0.f, 0.f};
  for (int nn = lo + r; nn < hi; nn += 16) {
    bf16x8 v = *(const bf16x8*)(x + (size_t)nn * DIM + c * 8);
    #pragma unroll
    for (int e = 0; e < 8; ++e) acc[e] += bf2f((unsigned short)v[e]);
  }
  #pragma unroll
  for (int e = 0; e < 8; ++e) part[r * PP + c * 8 + e] = acc[e];
  __syncthreads();
  if (t < DIM) {
    float s = 0.f;
    #pragma unroll
    for (int rr = 0; rr < 16; ++rr) s += part[rr * PP + t];
    pooled[t] = s / fmaxf((float)(hi - lo), 1.0f);
  }
  __syncthreads();
  if (t < ODIM) {
    float a = fcb[t];
    const float* wr = fcw + (size_t)t * DIM;
    #pragma unroll 8
    for (int h = 0; h < DIM; ++h) a += pooled[h] * wr[h];
    out[(size_t)g * ODIM + t] = a;
  }
}

// ---------------------------------------------------------------- launch
extern "C" void kernel_launch(void* const* d_in, const int* in_sizes, int n_in,
                              void* d_out, int out_size, void* d_ws, size_t ws_size,
                              hipStream_t stream) {
  const float* emb  = (const float*)d_in[0];
  const float* w1a  = (const float*)d_in[1];
  const float* b1a  = (const float*)d_in[2];
  const float* w1b  = (const float*)d_in[3];
  const float* b1b  = (const float*)d_in[4];
  const float* w2a  = (const float*)d_in[5];
  const float* b2a  = (const float*)d_in[6];
  const float* w2b  = (const float*)d_in[7];
  const float* b2b  = (const float*)d_in[8];
  const float* fcw  = (const float*)d_in[9];
  const float* fcb  = (const float*)d_in[10];
  const int*   xidx = (const int*)d_in[11];
  const int*   ei   = (const int*)d_in[12];
  const int*   batch= (const int*)d_in[13];
  float* out = (float*)d_out;

  size_t featb = (size_t)N_NODES * DIM * sizeof(unsigned short);  // 12.8 MB
  char* ws = (char*)d_ws;
  unsigned short* B1 = (unsigned short*)ws;             // xa (conv in)
  unsigned short* B2 = (unsigned short*)(ws + featb);   // conv out
  char* p = ws + 2 * featb;
  unsigned short* embb = (unsigned short*)p;  p += (VOCAB * DIM * 2 + 15) / 16 * 16;
  unsigned short* wbf  = (unsigned short*)p;  p += (4 * DIM * DIM * 2 + 15) / 16 * 16;  // 128 KB
  int* row  = (int*)p;      p += ((N_NODES + 1) * 4 + 15) / 16 * 16;
  int* bktbase = (int*)p;   p += ((NBKT + 1) * 4 + 15) / 16 * 16;
  unsigned* HB  = (unsigned*)p;  p += (size_t)NB2 * NBKT * 4;    // 200 KB
  unsigned* OFF = (unsigned*)p;  p += (size_t)NB2 * NBKT * 4;    // 200 KB
  unsigned* tot = (unsigned*)p;  p += (NBKT * 4 + 15) / 16 * 16;
  unsigned* eb  = (unsigned*)p;  p += (size_t)N_EDGES * 4;       // 3.2 MB
  int* srt  = (int*)p;      // N_EDGES ints (3.2 MB)

  const unsigned short* w1abf = wbf;
  const unsigned short* w1bbf = wbf + DIM * DIM;
  const unsigned short* w2abf = wbf + 2 * DIM * DIM;
  const unsigned short* w2bbf = wbf + 3 * DIM * DIM;

  emb2bf_kernel<<<(VOCAB * 16 + 255) / 256, 256, 0, stream>>>(emb, embb);
  w2bf_kernel<<<32, 256, 0, stream>>>(w1a, w1b, w2a, w2b, wbf);

  // CSR build: bucket-partition -> per-bucket LDS counting sort (coalesced srt writes)
  bkt_hist_kernel<<<NB2, 512, 0, stream>>>(ei, HB);
  col_scan_kernel<<<NBKT, 128, 0, stream>>>(HB, OFF, tot);
  base_scan_kernel<<<1, 512, 0, stream>>>(tot, bktbase, row);
  bkt_scatter_kernel<<<NB2, 512, 0, stream>>>(ei, OFF, bktbase, eb);
  sort_bucket_kernel<<<NBKT, 256, 0, stream>>>(eb, bktbase, srt, row);

  // conv1: gather from L2-resident emb table
  agg_emb_kernel<<<N_NODES / 16, 256, 0, stream>>>(embb, xidx, row, srt, B1);
  mlp_mfma_kernel<<<(N_NODES + 63) / 64, 256, 0, stream>>>(B1, w1abf, b1a, w1bbf, b1b, B2);

  // conv2: gather from node features
  agg_x_kernel<<<N_NODES / 16, 256, 0, stream>>>(B2, row, srt, B1);
  mlp_mfma_kernel<<<(N_NODES + 63) / 64, 256, 0, stream>>>(B1, w2abf, b2a, w2bbf, b2b, B2);

  pool_fc_kernel<<<NGRAPH, 256, 0, stream>>>(B2, batch, fcw, fcb, out);
}

// Round 11
// 131.465 us; speedup vs baseline: 3.0117x; 1.0237x over previous
//
#include <hip/hip_runtime.h>

#define N_NODES 50000
#define N_EDGES 800000
#define DIM 128
#define NGRAPH 512
#define ODIM 64
#define VOCAB 500
#define NBKT 391              // ceil(50000/128) coarse dst-buckets (128 nodes each)
#define NB2 128               // edge partitions
#define EPB2 (N_EDGES / NB2)  // 6250
#define CAP 4096              // max edges per bucket staged in LDS (mean 2046)

typedef __attribute__((ext_vector_type(8))) short bf16x8;
typedef __attribute__((ext_vector_type(4))) short bf16x4;
typedef __attribute__((ext_vector_type(4))) float f32x4;

__device__ inline unsigned short f2bf(float f) {
  unsigned u = __builtin_bit_cast(unsigned, f);
  return (unsigned short)((u + 0x7fffu + ((u >> 16) & 1u)) >> 16);
}
__device__ inline float bf2f(unsigned short h) {
  unsigned u = ((unsigned)h) << 16;
  return __builtin_bit_cast(float, u);
}

// ---------------------------------------------------------------- prep: emb + weights f32 -> bf16
__global__ __launch_bounds__(256) void prep_kernel(
    const float* __restrict__ emb,
    const float* __restrict__ w1a, const float* __restrict__ w1b,
    const float* __restrict__ w2a, const float* __restrict__ w2b,
    unsigned short* __restrict__ embb, unsigned short* __restrict__ wbf) {
  int u = blockIdx.x * 256 + threadIdx.x;   // one bf16x8 unit (8 elems)
  const float* src;
  unsigned short* dst;
  if (u < VOCAB * 16) {                     // 8000 units of emb
    src = emb + (size_t)u * 8;
    dst = embb + (size_t)u * 8;
  } else {
    int v = u - VOCAB * 16;                 // 4 x 2048 units of weights
    if (v >= 4 * 2048) return;
    int m = v >> 11, loc = v & 2047;
    const float* w = (m == 0) ? w1a : (m == 1) ? w1b : (m == 2) ? w2a : w2b;
    src = w + (size_t)loc * 8;
    dst = wbf + (size_t)v * 8;
  }
  f32x4 a = ((const f32x4*)src)[0], b = ((const f32x4*)src)[1];
  bf16x8 o;
  #pragma unroll
  for (int e = 0; e < 4; ++e) {
    o[e] = (short)f2bf(a[e]);
    o[4 + e] = (short)f2bf(b[e]);
  }
  *(bf16x8*)dst = o;
}

// ---------------------------------------------------------------- CSR build (3 kernels)
// pass 1: per-partition coarse-bucket histogram
__global__ __launch_bounds__(512) void bkt_hist_kernel(
    const int* __restrict__ ei, unsigned* __restrict__ HB) {
  __shared__ unsigned cnt[NBKT];
  int t = threadIdx.x, b = blockIdx.x;
  for (int i = t; i < NBKT; i += 512) cnt[i] = 0;
  __syncthreads();
  int base = b * EPB2;
  for (int i = t; i < EPB2; i += 512)
    atomicAdd(&cnt[(unsigned)ei[N_EDGES + base + i] >> 7], 1u);
  __syncthreads();
  for (int i = t; i < NBKT; i += 512) HB[(size_t)b * NBKT + i] = cnt[i];
}

// pass 2: scatter to coarse buckets; block b computes its own prefix + bktbase from HB
__global__ __launch_bounds__(512) void bkt_scatter_kernel(
    const int* __restrict__ ei, const unsigned* __restrict__ HB,
    unsigned* __restrict__ eb) {
  __shared__ unsigned cur[NBKT];
  __shared__ unsigned wsum[8];
  int t = threadIdx.x, b = blockIdx.x;
  int lane = t & 63, wid = t >> 6;
  unsigned pre = 0, tot = 0;
  if (t < NBKT) {
    for (int bb = 0; bb < NB2; ++bb) {          // coalesced row-wise reads
      unsigned h = HB[(size_t)bb * NBKT + t];
      pre += (bb < b) ? h : 0u;
      tot += h;
    }
  }
  unsigned s = tot;                              // exclusive scan of tot -> bktbase
  #pragma unroll
  for (int d = 1; d < 64; d <<= 1) {
    unsigned u = __shfl_up(s, d, 64);
    if (lane >= d) s += u;
  }
  if (lane == 63) wsum[wid] = s;
  __syncthreads();
  if (wid == 0) {
    unsigned ws = (lane < 8) ? wsum[lane] : 0u;
    #pragma unroll
    for (int d = 1; d < 8; d <<= 1) {
      unsigned u = __shfl_up(ws, d, 64);
      if (lane >= d) ws += u;
    }
    if (lane < 8) wsum[lane] = ws;
  }
  __syncthreads();
  unsigned base = s - tot + (wid ? wsum[wid - 1] : 0u);
  if (t < NBKT) cur[t] = base + pre;
  __syncthreads();
  int ebase = b * EPB2;
  for (int i = t; i < EPB2; i += 512) {
    int sn = ei[ebase + i];
    unsigned d = (unsigned)ei[N_EDGES + ebase + i];
    unsigned pos = atomicAdd(&cur[d >> 7], 1u);
    eb[pos] = ((d & 127u) << 16) | (unsigned)sn;
  }
}

// pass 3: per-bucket LDS counting sort -> coalesced srt + row; bktbase recomputed in-block
__global__ __launch_bounds__(512) void sort_bucket_kernel(
    const unsigned* __restrict__ HB, const unsigned* __restrict__ eb,
    int* __restrict__ srt, int* __restrict__ row) {
  __shared__ unsigned stage[CAP];        // 16 KB
  __shared__ unsigned short sorted[CAP]; // 8 KB
  __shared__ unsigned hist[128], cur[128];
  __shared__ unsigned wtot, wsum[8];
  __shared__ int sbound[2];
  int t = threadIdx.x, bkt = blockIdx.x;
  int lane = t & 63, wid = t >> 6;
  unsigned tot = 0;
  if (t < NBKT)
    for (int bb = 0; bb < NB2; ++bb) tot += HB[(size_t)bb * NBKT + t];
  unsigned s = tot;
  #pragma unroll
  for (int d = 1; d < 64; d <<= 1) {
    unsigned u = __shfl_up(s, d, 64);
    if (lane >= d) s += u;
  }
  if (lane == 63) wsum[wid] = s;
  __syncthreads();
  if (wid == 0) {
    unsigned ws = (lane < 8) ? wsum[lane] : 0u;
    #pragma unroll
    for (int d = 1; d < 8; d <<= 1) {
      unsigned u = __shfl_up(ws, d, 64);
      if (lane >= d) ws += u;
    }
    if (lane < 8) wsum[lane] = ws;
  }
  __syncthreads();
  unsigned base = s - tot + (wid ? wsum[wid - 1] : 0u);
  if (t == bkt) { sbound[0] = (int)base; sbound[1] = (int)(base + tot); }
  if (t < 128) hist[t] = 0;
  if (bkt == 0 && t == 0) row[N_NODES] = N_EDGES;
  __syncthreads();
  int bs = sbound[0];
  int cnt = sbound[1] - bs;
  if (cnt > CAP) cnt = CAP;   // statistically impossible; guards LDS
  for (int i = t; i < cnt; i += 512) {
    unsigned e = eb[bs + i];
    stage[i] = e;
    atomicAdd(&hist[e >> 16], 1u);
  }
  __syncthreads();
  if (t < 128) {                         // exclusive scan of 128 node counters
    unsigned v = hist[t], ss = v;
    #pragma unroll
    for (int d = 1; d < 64; d <<= 1) {
      unsigned u = __shfl_up(ss, d, 64);
      if (lane >= d) ss += u;
    }
    if (t == 63) wtot = ss;
    cur[t] = ss - v;                     // wave-local exclusive
  }
  __syncthreads();
  if (t < 128) {
    unsigned e0 = cur[t] + (t >= 64 ? wtot : 0u);
    cur[t] = e0;
    int n = bkt * 128 + t;
    if (n < N_NODES) row[n] = bs + (int)e0;
  }
  __syncthreads();
  for (int i = t; i < cnt; i += 512) {
    unsigned e = stage[i];
    unsigned r = atomicAdd(&cur[e >> 16], 1u);
    sorted[r] = (unsigned short)(e & 0xFFFFu);
  }
  __syncthreads();
  for (int i = t; i < cnt; i += 512) srt[bs + i] = (int)sorted[i];
}

// ---------------------------------------------------------------- agg (conv1): from emb table
// 16 lanes/node, bf16x8 (16 B) per lane; 16 nodes per 256-block; 8-deep gather unroll
__global__ __launch_bounds__(256) void agg_emb_kernel(
    const unsigned short* __restrict__ embb, const int* __restrict__ xidx,
    const int* __restrict__ row, const int* __restrict__ srt,
    unsigned short* __restrict__ xa) {
  int n = blockIdx.x * 16 + (threadIdx.x >> 4);
  int c = threadIdx.x & 15;
  int lo = row[n], hi = row[n + 1];
  bf16x8 sv = *(const bf16x8*)(embb + (size_t)xidx[n] * DIM + c * 8);
  float a[8];
  #pragma unroll
  for (int e = 0; e < 8; ++e) a[e] = bf2f((unsigned short)sv[e]);
  int k = lo;
  for (; k + 8 <= hi; k += 8) {
    bf16x8 w[8];
    #pragma unroll
    for (int q = 0; q < 8; ++q)
      w[q] = *(const bf16x8*)(embb + (size_t)xidx[srt[k + q]] * DIM + c * 8);
    #pragma unroll
    for (int q = 0; q < 8; ++q)
      #pragma unroll
      for (int e = 0; e < 8; ++e) a[e] += bf2f((unsigned short)w[q][e]);
  }
  for (; k + 2 <= hi; k += 2) {
    bf16x8 w0 = *(const bf16x8*)(embb + (size_t)xidx[srt[k]] * DIM + c * 8);
    bf16x8 w1 = *(const bf16x8*)(embb + (size_t)xidx[srt[k + 1]] * DIM + c * 8);
    #pragma unroll
    for (int e = 0; e < 8; ++e)
      a[e] += bf2f((unsigned short)w0[e]) + bf2f((unsigned short)w1[e]);
  }
  if (k < hi) {
    bf16x8 w = *(const bf16x8*)(embb + (size_t)xidx[srt[k]] * DIM + c * 8);
    #pragma unroll
    for (int e = 0; e < 8; ++e) a[e] += bf2f((unsigned short)w[e]);
  }
  bf16x8 o;
  #pragma unroll
  for (int e = 0; e < 8; ++e) o[e] = (short)f2bf(a[e]);
  *(bf16x8*)(xa + (size_t)n * DIM + c * 8) = o;
}

// ---------------------------------------------------------------- agg (conv2): from node features
__global__ __launch_bounds__(256) void agg_x_kernel(
    const unsigned short* __restrict__ x, const int* __restrict__ row,
    const int* __restrict__ srt, unsigned short* __restrict__ xa) {
  int n = blockIdx.x * 16 + (threadIdx.x >> 4);
  int c = threadIdx.x & 15;
  int lo = row[n], hi = row[n + 1];
  bf16x8 sv = *(const bf16x8*)(x + (size_t)n * DIM + c * 8);
  float a[8];
  #pragma unroll
  for (int e = 0; e < 8; ++e) a[e] = bf2f((unsigned short)sv[e]);
  int k = lo;
  for (; k + 8 <= hi; k += 8) {
    bf16x8 w[8];
    #pragma unroll
    for (int q = 0; q < 8; ++q)
      w[q] = *(const bf16x8*)(x + (size_t)srt[k + q] * DIM + c * 8);
    #pragma unroll
    for (int q = 0; q < 8; ++q)
      #pragma unroll
      for (int e = 0; e < 8; ++e) a[e] += bf2f((unsigned short)w[q][e]);
  }
  for (; k + 2 <= hi; k += 2) {
    bf16x8 w0 = *(const bf16x8*)(x + (size_t)srt[k] * DIM + c * 8);
    bf16x8 w1 = *(const bf16x8*)(x + (size_t)srt[k + 1] * DIM + c * 8);
    #pragma unroll
    for (int e = 0; e < 8; ++e)
      a[e] += bf2f((unsigned short)w0[e]) + bf2f((unsigned short)w1[e]);
  }
  if (k < hi) {
    bf16x8 w = *(const bf16x8*)(x + (size_t)srt[k] * DIM + c * 8);
    #pragma unroll
    for (int e = 0; e < 8; ++e) a[e] += bf2f((unsigned short)w[e]);
  }
  bf16x8 o;
  #pragma unroll
  for (int e = 0; e < 8; ++e) o[e] = (short)f2bf(a[e]);
  *(bf16x8*)(xa + (size_t)n * DIM + c * 8) = o;
}

// ---------------------------------------------------------------- MFMA 2-layer MLP (bf16 weights)
// 128 nodes/block in two 64-node halves; weight fragments loaded once per block.
__global__ __launch_bounds__(256) void mlp_mfma_kernel(
    const unsigned short* __restrict__ xa,
    const unsigned short* __restrict__ wabf, const float* __restrict__ ba,
    const unsigned short* __restrict__ wbbf, const float* __restrict__ bb,
    unsigned short* __restrict__ xout) {
  __shared__ short Xs[64 * 128];   // 16 KB, 16B-chunk XOR swizzle (chunk ^= row&7)
  __shared__ short Hs[64 * 128];   // 16 KB
  int t = threadIdx.x;
  int lane = t & 63;
  int w = t >> 6;
  int jq = w * 32;
  int l15 = lane & 15;
  int lg = lane >> 4;

  bf16x8 waf[2][4], wbf[2][4];
  #pragma unroll
  for (int jm = 0; jm < 2; ++jm) {
    int jrow = jq + jm * 16 + l15;
    #pragma unroll
    for (int ks = 0; ks < 4; ++ks) {
      int k0 = ks * 32 + lg * 8;
      waf[jm][ks] = *(const bf16x8*)(wabf + (size_t)jrow * DIM + k0);
      wbf[jm][ks] = *(const bf16x8*)(wbbf + (size_t)jrow * DIM + k0);
    }
  }
  f32x4 ba_r[2], bb_r[2];
  #pragma unroll
  for (int jm = 0; jm < 2; ++jm) {
    ba_r[jm] = *(const f32x4*)(ba + jq + jm * 16 + lg * 4);
    bb_r[jm] = *(const f32x4*)(bb + jq + jm * 16 + lg * 4);
  }

  for (int half = 0; half < 2; ++half) {
    int nbase = blockIdx.x * 128 + half * 64;

    {
      int r = t >> 2;
      int cb = (t & 3) * 4;
      int node = nbase + r;
      #pragma unroll
      for (int i = 0; i < 4; ++i) {
        int chunk = cb + i;
        bf16x8 v = {0, 0, 0, 0, 0, 0, 0, 0};
        if (node < N_NODES)
          v = *(const bf16x8*)(xa + (size_t)node * DIM + chunk * 8);
        *(bf16x8*)&Xs[r * 128 + ((chunk ^ (r & 7)) << 3)] = v;
      }
    }
    __syncthreads();

    #pragma unroll
    for (int nt = 0; nt < 4; ++nt) {
      int rrow = nt * 16 + l15;
      bf16x8 xf[4];
      #pragma unroll
      for (int ks = 0; ks < 4; ++ks) {
        int chunk = ks * 4 + lg;
        xf[ks] = *(const bf16x8*)&Xs[rrow * 128 + ((chunk ^ (rrow & 7)) << 3)];
      }
      #pragma unroll
      for (int jm = 0; jm < 2; ++jm) {
        f32x4 acc = ba_r[jm];
        #pragma unroll
        for (int ks = 0; ks < 4; ++ks)
          acc = __builtin_amdgcn_mfma_f32_16x16x32_bf16(waf[jm][ks], xf[ks], acc, 0, 0, 0);
        int hnode = nt * 16 + l15;
        int cbase = jq + jm * 16 + lg * 4;
        unsigned p0 = (unsigned)f2bf(fmaxf(acc[0], 0.f)) |
                      ((unsigned)f2bf(fmaxf(acc[1], 0.f)) << 16);
        unsigned p1 = (unsigned)f2bf(fmaxf(acc[2], 0.f)) |
                      ((unsigned)f2bf(fmaxf(acc[3], 0.f)) << 16);
        unsigned idx = hnode * 128 + (((cbase >> 3) ^ (hnode & 7)) << 3) + (cbase & 7);
        *(uint2*)&Hs[idx] = make_uint2(p0, p1);
      }
    }
    __syncthreads();

    #pragma unroll
    for (int nt = 0; nt < 4; ++nt) {
      int rrow = nt * 16 + l15;
      bf16x8 hf[4];
      #pragma unroll
      for (int ks = 0; ks < 4; ++ks) {
        int chunk = ks * 4 + lg;
        hf[ks] = *(const bf16x8*)&Hs[rrow * 128 + ((chunk ^ (rrow & 7)) << 3)];
      }
      #pragma unroll
      for (int jm = 0; jm < 2; ++jm) {
        f32x4 acc = bb_r[jm];
        #pragma unroll
        for (int ks = 0; ks < 4; ++ks)
          acc = __builtin_amdgcn_mfma_f32_16x16x32_bf16(wbf[jm][ks], hf[ks], acc, 0, 0, 0);
        int node = nbase + nt * 16 + l15;
        if (node < N_NODES) {
          bf16x4 o;
          #pragma unroll
          for (int e = 0; e < 4; ++e) o[e] = (short)f2bf(fmaxf(acc[e], 0.f));
          *(bf16x4*)(xout + (size_t)node * DIM + jq + jm * 16 + lg * 4) = o;
        }
      }
    }
    __syncthreads();   // protect Xs/Hs before next half's staging/GEMM1
  }
}

// ---------------------------------------------------------------- mean-pool + FC (row-parallel)
#define PP 132
__global__ __launch_bounds__(256) void pool_fc_kernel(
    const unsigned short* __restrict__ x, const int* __restrict__ batch,
    const float* __restrict__ fcw, const float* __restrict__ fcb,
    float* __restrict__ out) {
  int g = blockIdx.x, t = threadIdx.x;
  __shared__ float part[16 * PP];
  __shared__ float pooled[DIM];
  __shared__ int sbound[2];
  if (t < 2) {
    int target = g + t;
    int lo = 0, hi = N_NODES;
    while (lo < hi) {
      int m = (lo + hi) >> 1;
      if (batch[m] < target) lo = m + 1; else hi = m;
    }
    sbound[t] = lo;
  }
  __syncthreads();
  int lo = sbound[0], hi = sbound[1];
  int r = t >> 4, c = t & 15;
  float acc[8] = {0.f, 0.f, 0.f, 0.f, 0.f, 0.f, 0.f, 0.f};
  for (int nn = lo + r; nn < hi; nn += 16) {
    bf16x8 v = *(const bf16x8*)(x + (size_t)nn * DIM + c * 8);
    #pragma unroll
    for (int e = 0; e < 8; ++e) acc[e] += bf2f((unsigned short)v[e]);
  }
  #pragma unroll
  for (int e = 0; e < 8; ++e) part[r * PP + c * 8 + e] = acc[e];
  __syncthreads();
  if (t < DIM) {
    float s = 0.f;
    #pragma unroll
    for (int rr = 0; rr < 16; ++rr) s += part[rr * PP + t];
    pooled[t] = s / fmaxf((float)(hi - lo), 1.0f);
  }
  __syncthreads();
  if (t < ODIM) {
    float a = fcb[t];
    const float* wr = fcw + (size_t)t * DIM;
    #pragma unroll 8
    for (int h = 0; h < DIM; ++h) a += pooled[h] * wr[h];
    out[(size_t)g * ODIM + t] = a;
  }
}

// ---------------------------------------------------------------- launch
extern "C" void kernel_launch(void* const* d_in, const int* in_sizes, int n_in,
                              void* d_out, int out_size, void* d_ws, size_t ws_size,
                              hipStream_t stream) {
  const float* emb  = (const float*)d_in[0];
  const float* w1a  = (const float*)d_in[1];
  const float* b1a  = (const float*)d_in[2];
  const float* w1b  = (const float*)d_in[3];
  const float* b1b  = (const float*)d_in[4];
  const float* w2a  = (const float*)d_in[5];
  const float* b2a  = (const float*)d_in[6];
  const float* w2b  = (const float*)d_in[7];
  const float* b2b  = (const float*)d_in[8];
  const float* fcw  = (const float*)d_in[9];
  const float* fcb  = (const float*)d_in[10];
  const int*   xidx = (const int*)d_in[11];
  const int*   ei   = (const int*)d_in[12];
  const int*   batch= (const int*)d_in[13];
  float* out = (float*)d_out;

  size_t featb = (size_t)N_NODES * DIM * sizeof(unsigned short);  // 12.8 MB
  char* ws = (char*)d_ws;
  unsigned short* B1 = (unsigned short*)ws;             // xa (conv in)
  unsigned short* B2 = (unsigned short*)(ws + featb);   // conv out
  char* p = ws + 2 * featb;
  unsigned short* embb = (unsigned short*)p;  p += (VOCAB * DIM * 2 + 15) / 16 * 16;
  unsigned short* wbf  = (unsigned short*)p;  p += (4 * DIM * DIM * 2 + 15) / 16 * 16;  // 128 KB
  int* row  = (int*)p;      p += ((N_NODES + 1) * 4 + 15) / 16 * 16;
  unsigned* HB  = (unsigned*)p;  p += (size_t)NB2 * NBKT * 4;    // 200 KB
  unsigned* eb  = (unsigned*)p;  p += (size_t)N_EDGES * 4;       // 3.2 MB
  int* srt  = (int*)p;      // N_EDGES ints (3.2 MB)

  const unsigned short* w1abf = wbf;
  const unsigned short* w1bbf = wbf + DIM * DIM;
  const unsigned short* w2abf = wbf + 2 * DIM * DIM;
  const unsigned short* w2bbf = wbf + 3 * DIM * DIM;

  prep_kernel<<<(VOCAB * 16 + 4 * 2048 + 255) / 256, 256, 0, stream>>>(
      emb, w1a, w1b, w2a, w2b, embb, wbf);

  // CSR build: hist -> bucket scatter -> per-bucket counting sort (3 kernels)
  bkt_hist_kernel<<<NB2, 512, 0, stream>>>(ei, HB);
  bkt_scatter_kernel<<<NB2, 512, 0, stream>>>(ei, HB, eb);
  sort_bucket_kernel<<<NBKT, 512, 0, stream>>>(HB, eb, srt, row);

  // conv1: gather from L2-resident emb table
  agg_emb_kernel<<<N_NODES / 16, 256, 0, stream>>>(embb, xidx, row, srt, B1);
  mlp_mfma_kernel<<<(N_NODES + 127) / 128, 256, 0, stream>>>(B1, w1abf, b1a, w1bbf, b1b, B2);

  // conv2: gather from node features
  agg_x_kernel<<<N_NODES / 16, 256, 0, stream>>>(B2, row, srt, B1);
  mlp_mfma_kernel<<<(N_NODES + 127) / 128, 256, 0, stream>>>(B1, w2abf, b2a, w2bbf, b2b, B2);

  pool_fc_kernel<<<NGRAPH, 256, 0, stream>>>(B2, batch, fcw, fcb, out);
}